// Round 2
// baseline (1605.350 us; speedup 1.0000x reference)
//
#include <hip/hip_runtime.h>
#include <math.h>

#define N_NODES 51200
#define N_EDGES 640000
#define N_TYPES 4
#define N_RELS  8
#define N_HEADS 4
#define D_K     32
#define DIM     128
#define NODES_PER_TYPE (N_NODES / N_TYPES)   // 12800
#define EDGES_PER_REL  (N_EDGES / N_RELS)    // 80000
#define INV_SQRT_DK 0.17677669529663687f

__global__ __launch_bounds__(256) void zero_kernel(float* __restrict__ p, int n4) {
    int i = blockIdx.x * blockDim.x + threadIdx.x;
    if (i < n4) ((float4*)p)[i] = make_float4(0.f, 0.f, 0.f, 0.f);
}

// Per-node-type projection GEMM: out[n][o] = sum_d x[n][d] * W[type(n)][d][o]
__global__ __launch_bounds__(256) void proj_kernel(
    const float* __restrict__ h,
    const float* __restrict__ Wk,
    const float* __restrict__ Wq,
    const float* __restrict__ Wv,
    float* __restrict__ kf, float* __restrict__ qf, float* __restrict__ vf)
{
    __shared__ float hs[64][132];
    const int tid = threadIdx.x;
    const int which = blockIdx.y;
    const float* W = (which == 0) ? Wk : (which == 1) ? Wq : Wv;
    float* outp    = (which == 0) ? kf : (which == 1) ? qf : vf;
    const int n0 = blockIdx.x * 64;
    const int t = n0 / NODES_PER_TYPE;
    const float* Wt = W + (size_t)t * DIM * DIM;

    const float4* hsrc = (const float4*)(h + (size_t)n0 * DIM);
    #pragma unroll
    for (int i = 0; i < 8; ++i) {
        int f = tid + i * 256;
        *(float4*)&hs[f >> 5][(f & 31) * 4] = hsrc[f];
    }
    __syncthreads();

    const int ty = tid >> 4, tx = tid & 15;
    float acc[4][8];
    #pragma unroll
    for (int i = 0; i < 4; ++i)
        #pragma unroll
        for (int j = 0; j < 8; ++j) acc[i][j] = 0.f;

    #pragma unroll 2
    for (int d = 0; d < DIM; ++d) {
        const float* wrow = Wt + d * DIM + tx * 8;
        float4 w0 = *(const float4*)wrow;
        float4 w1 = *(const float4*)(wrow + 4);
        float hv[4];
        #pragma unroll
        for (int i = 0; i < 4; ++i) hv[i] = hs[ty * 4 + i][d];
        #pragma unroll
        for (int i = 0; i < 4; ++i) {
            acc[i][0] = fmaf(hv[i], w0.x, acc[i][0]);
            acc[i][1] = fmaf(hv[i], w0.y, acc[i][1]);
            acc[i][2] = fmaf(hv[i], w0.z, acc[i][2]);
            acc[i][3] = fmaf(hv[i], w0.w, acc[i][3]);
            acc[i][4] = fmaf(hv[i], w1.x, acc[i][4]);
            acc[i][5] = fmaf(hv[i], w1.y, acc[i][5]);
            acc[i][6] = fmaf(hv[i], w1.z, acc[i][6]);
            acc[i][7] = fmaf(hv[i], w1.w, acc[i][7]);
        }
    }
    #pragma unroll
    for (int i = 0; i < 4; ++i) {
        float* orow = outp + (size_t)(n0 + ty * 4 + i) * DIM + tx * 8;
        *(float4*)orow       = make_float4(acc[i][0], acc[i][1], acc[i][2], acc[i][3]);
        *(float4*)(orow + 4) = make_float4(acc[i][4], acc[i][5], acc[i][6], acc[i][7]);
    }
}

// Per-relation node transform: tf[n][h*32+j] = sum_k src[n][h*32+k] * W[h][k][j]
// W points at one relation's [4][32][32] slice. Dense GEMM, 64 nodes/block.
__global__ __launch_bounds__(256) void trans_kernel(
    const float* __restrict__ src,
    const float* __restrict__ W,
    float* __restrict__ tf)
{
    // hs: head-swizzled (+4 floats per head) -> banks spread across heads
    __shared__ float hs[64][140];
    __shared__ float Ws[4124];   // 4 heads * (1024 + 4 pad)
    const int tid = threadIdx.x;
    const int n0 = blockIdx.x * 64;

    const float4* hsrc = (const float4*)(src + (size_t)n0 * DIM);
    #pragma unroll
    for (int i = 0; i < 8; ++i) {
        int f = tid + i * 256;
        int row = f >> 5, c4 = f & 31;
        int pc4 = c4 + (c4 >> 3);            // +1 float4 per head block
        *(float4*)&hs[row][pc4 * 4] = hsrc[f];
    }
    #pragma unroll
    for (int i = 0; i < 16; ++i) {
        int g = tid + i * 256;
        Ws[(g >> 10) * 1028 + (g & 1023)] = W[g];
    }
    __syncthreads();

    const int ty = tid >> 4, tx = tid & 15;
    const int hh = tx >> 2, j8 = (tx & 3) * 8;
    const float* wsb = &Ws[hh * 1028 + j8];
    float acc[4][8];
    #pragma unroll
    for (int i = 0; i < 4; ++i)
        #pragma unroll
        for (int j = 0; j < 8; ++j) acc[i][j] = 0.f;

    #pragma unroll 4
    for (int kk = 0; kk < 32; ++kk) {
        float4 w0 = *(const float4*)(wsb + kk * 32);
        float4 w1 = *(const float4*)(wsb + kk * 32 + 4);
        float hv[4];
        #pragma unroll
        for (int i = 0; i < 4; ++i) hv[i] = hs[ty * 4 + i][hh * 36 + kk];
        #pragma unroll
        for (int i = 0; i < 4; ++i) {
            acc[i][0] = fmaf(hv[i], w0.x, acc[i][0]);
            acc[i][1] = fmaf(hv[i], w0.y, acc[i][1]);
            acc[i][2] = fmaf(hv[i], w0.z, acc[i][2]);
            acc[i][3] = fmaf(hv[i], w0.w, acc[i][3]);
            acc[i][4] = fmaf(hv[i], w1.x, acc[i][4]);
            acc[i][5] = fmaf(hv[i], w1.y, acc[i][5]);
            acc[i][6] = fmaf(hv[i], w1.z, acc[i][6]);
            acc[i][7] = fmaf(hv[i], w1.w, acc[i][7]);
        }
    }
    #pragma unroll
    for (int i = 0; i < 4; ++i) {
        float* orow = tf + (size_t)(n0 + ty * 4 + i) * DIM + hh * 32 + j8;
        *(float4*)orow       = make_float4(acc[i][0], acc[i][1], acc[i][2], acc[i][3]);
        *(float4*)(orow + 4) = make_float4(acc[i][4], acc[i][5], acc[i][6], acc[i][7]);
    }
}

// Light edge score: s[e][h] = dot32(tf[dst][h], kf[src][h]) * pri; exp + denom atomic.
// 32 lanes/edge (float4 each), 8 edges in flight per block, 32 edges/block total.
__global__ __launch_bounds__(256) void score_light(
    const float* __restrict__ tf, const float* __restrict__ kf,
    const float* __restrict__ pri,
    const int* __restrict__ row_idx, const int* __restrict__ col_idx,
    float* __restrict__ evals, float* __restrict__ denom,
    int e0, int r)
{
    const int tid = threadIdx.x;
    const int lane = tid & 31;
    const int hh = lane >> 3;
    const int eslot = tid >> 5;
    const float prih = pri[r * N_HEADS + hh] * INV_SQRT_DK;
    int e = e0 + blockIdx.x * 32 + eslot;
    #pragma unroll
    for (int it = 0; it < 4; ++it, e += 8) {
        const int src = row_idx[e];
        const int dst = col_idx[e];
        float4 a = *(const float4*)(tf + (size_t)dst * DIM + lane * 4);
        float4 b = *(const float4*)(kf + (size_t)src * DIM + lane * 4);
        float p = a.x * b.x + a.y * b.y + a.z * b.z + a.w * b.w;
        p += __shfl_xor(p, 1);
        p += __shfl_xor(p, 2);
        p += __shfl_xor(p, 4);
        if ((lane & 7) == 0) {
            float ev = expf(p * prih);
            evals[(size_t)e * N_HEADS + hh] = ev;
            atomicAdd(denom + (size_t)dst * N_HEADS + hh, ev);
        }
    }
}

// Light message aggregation: agg[dst] += (ev/denom) * tf_v[src]
__global__ __launch_bounds__(256) void msg_light(
    const float* __restrict__ tf,
    const int* __restrict__ row_idx, const int* __restrict__ col_idx,
    const float* __restrict__ evals, const float* __restrict__ denom,
    float* __restrict__ agg, int e0)
{
    const int tid = threadIdx.x;
    const int lane = tid & 31;
    const int hh = lane >> 3;
    const int eslot = tid >> 5;
    int e = e0 + blockIdx.x * 32 + eslot;
    #pragma unroll
    for (int it = 0; it < 4; ++it, e += 8) {
        const int src = row_idx[e];
        const int dst = col_idx[e];
        float4 v4 = *(const float4*)(tf + (size_t)src * DIM + lane * 4);
        float alpha = evals[(size_t)e * N_HEADS + hh]
                    / (denom[(size_t)dst * N_HEADS + hh] + 1e-16f);
        float* ap = agg + (size_t)dst * DIM + lane * 4;
        atomicAdd(ap + 0, alpha * v4.x);
        atomicAdd(ap + 1, alpha * v4.y);
        atomicAdd(ap + 2, alpha * v4.z);
        atomicAdd(ap + 3, alpha * v4.w);
    }
}

// Output projection with per-type sigmoid(skip) gate
__global__ __launch_bounds__(256) void out_kernel(
    const float* __restrict__ agg,
    const float* __restrict__ A,
    const float* __restrict__ skip,
    float* __restrict__ outp)
{
    __shared__ float hs[64][132];
    const int tid = threadIdx.x;
    const int n0 = blockIdx.x * 64;
    const int t = n0 / NODES_PER_TYPE;
    const float* Wt = A + (size_t)t * DIM * DIM;
    const float sg = 1.f / (1.f + expf(-skip[t]));

    const float4* hsrc = (const float4*)(agg + (size_t)n0 * DIM);
    #pragma unroll
    for (int i = 0; i < 8; ++i) {
        int f = tid + i * 256;
        *(float4*)&hs[f >> 5][(f & 31) * 4] = hsrc[f];
    }
    __syncthreads();

    const int ty = tid >> 4, tx = tid & 15;
    float acc[4][8];
    #pragma unroll
    for (int i = 0; i < 4; ++i)
        #pragma unroll
        for (int j = 0; j < 8; ++j) acc[i][j] = 0.f;

    #pragma unroll 2
    for (int d = 0; d < DIM; ++d) {
        const float* wrow = Wt + d * DIM + tx * 8;
        float4 w0 = *(const float4*)wrow;
        float4 w1 = *(const float4*)(wrow + 4);
        float hv[4];
        #pragma unroll
        for (int i = 0; i < 4; ++i) hv[i] = hs[ty * 4 + i][d];
        #pragma unroll
        for (int i = 0; i < 4; ++i) {
            acc[i][0] = fmaf(hv[i], w0.x, acc[i][0]);
            acc[i][1] = fmaf(hv[i], w0.y, acc[i][1]);
            acc[i][2] = fmaf(hv[i], w0.z, acc[i][2]);
            acc[i][3] = fmaf(hv[i], w0.w, acc[i][3]);
            acc[i][4] = fmaf(hv[i], w1.x, acc[i][4]);
            acc[i][5] = fmaf(hv[i], w1.y, acc[i][5]);
            acc[i][6] = fmaf(hv[i], w1.z, acc[i][6]);
            acc[i][7] = fmaf(hv[i], w1.w, acc[i][7]);
        }
    }
    #pragma unroll
    for (int i = 0; i < 4; ++i) {
        float* orow = outp + (size_t)(n0 + ty * 4 + i) * DIM + tx * 8;
        *(float4*)orow       = make_float4(sg*acc[i][0], sg*acc[i][1], sg*acc[i][2], sg*acc[i][3]);
        *(float4*)(orow + 4) = make_float4(sg*acc[i][4], sg*acc[i][5], sg*acc[i][6], sg*acc[i][7]);
    }
}

extern "C" void kernel_launch(void* const* d_in, const int* in_sizes, int n_in,
                              void* d_out, int out_size, void* d_ws, size_t ws_size,
                              hipStream_t stream) {
    (void)in_sizes; (void)n_in; (void)out_size; (void)ws_size;
    const float* h    = (const float*)d_in[0];
    const float* Wk   = (const float*)d_in[1];
    const float* Wq   = (const float*)d_in[2];
    const float* Wv   = (const float*)d_in[3];
    const float* Wa   = (const float*)d_in[4];
    const float* Watt = (const float*)d_in[5];
    const float* Wmsg = (const float*)d_in[6];
    const float* pri  = (const float*)d_in[7];
    const float* skip = (const float*)d_in[8];
    const int* row_idx = (const int*)d_in[9];
    const int* col_idx = (const int*)d_in[10];

    float* out = (float*)d_out;
    float* ws  = (float*)d_ws;

    // ws: [kf | qf | vf | tf] = 4 * N*128 floats = 104.9 MB.
    // agg overlays qf (q dead after score phase).
    // evals (E*4) + denom (N*4) staged in d_out (overwritten by out_kernel).
    float* kf = ws;
    float* qf = ws + (size_t)N_NODES * DIM;
    float* vf = ws + (size_t)2 * N_NODES * DIM;
    float* tf = ws + (size_t)3 * N_NODES * DIM;
    float* agg = qf;
    float* evals = out;
    float* denom = out + (size_t)N_EDGES * N_HEADS;

    const size_t REL_W = (size_t)N_HEADS * D_K * D_K;   // 4096 floats per relation

    // 1. zero softmax denominators
    zero_kernel<<<(N_NODES * N_HEADS / 4 + 255) / 256, 256, 0, stream>>>(denom, N_NODES * N_HEADS / 4);
    // 2. K/Q/V projections
    proj_kernel<<<dim3(N_NODES / 64, 3), 256, 0, stream>>>(h, Wk, Wq, Wv, kf, qf, vf);
    // 3. per relation: dense q-transform, then light edge scoring
    for (int r = 0; r < N_RELS; ++r) {
        trans_kernel<<<N_NODES / 64, 256, 0, stream>>>(qf, Watt + r * REL_W, tf);
        score_light<<<EDGES_PER_REL / 32, 256, 0, stream>>>(
            tf, kf, pri, row_idx, col_idx, evals, denom, r * EDGES_PER_REL, r);
    }
    // 4. zero agg (overlays qf — q dead now)
    zero_kernel<<<(N_NODES * DIM / 4 + 255) / 256, 256, 0, stream>>>(agg, N_NODES * DIM / 4);
    // 5. per relation: dense v-transform, then light aggregation
    for (int r = 0; r < N_RELS; ++r) {
        trans_kernel<<<N_NODES / 64, 256, 0, stream>>>(vf, Wmsg + r * REL_W, tf);
        msg_light<<<EDGES_PER_REL / 32, 256, 0, stream>>>(
            tf, row_idx, col_idx, evals, denom, agg, r * EDGES_PER_REL);
    }
    // 6. output projection
    out_kernel<<<N_NODES / 64, 256, 0, stream>>>(agg, Wa, skip, out);
}

// Round 3
// 1600.555 us; speedup vs baseline: 1.0030x; 1.0030x over previous
//
#include <hip/hip_runtime.h>
#include <math.h>

#define N_NODES 51200
#define N_EDGES 640000
#define N_TYPES 4
#define N_RELS  8
#define N_HEADS 4
#define D_K     32
#define DIM     128
#define NODES_PER_TYPE (N_NODES / N_TYPES)   // 12800
#define EDGES_PER_REL  (N_EDGES / N_RELS)    // 80000
#define INV_SQRT_DK 0.17677669529663687f

__global__ __launch_bounds__(256) void zero_kernel(float* __restrict__ p, int n4) {
    int i = blockIdx.x * blockDim.x + threadIdx.x;
    if (i < n4) ((float4*)p)[i] = make_float4(0.f, 0.f, 0.f, 0.f);
}

// ---------------- dense projections ----------------

__global__ __launch_bounds__(256) void proj_kernel(
    const float* __restrict__ h,
    const float* __restrict__ Wk,
    const float* __restrict__ Wq,
    const float* __restrict__ Wv,
    float* __restrict__ kf, float* __restrict__ qf, float* __restrict__ vf)
{
    __shared__ float hs[64][132];
    const int tid = threadIdx.x;
    const int which = blockIdx.y;
    const float* W = (which == 0) ? Wk : (which == 1) ? Wq : Wv;
    float* outp    = (which == 0) ? kf : (which == 1) ? qf : vf;
    const int n0 = blockIdx.x * 64;
    const int t = n0 / NODES_PER_TYPE;
    const float* Wt = W + (size_t)t * DIM * DIM;

    const float4* hsrc = (const float4*)(h + (size_t)n0 * DIM);
    #pragma unroll
    for (int i = 0; i < 8; ++i) {
        int f = tid + i * 256;
        *(float4*)&hs[f >> 5][(f & 31) * 4] = hsrc[f];
    }
    __syncthreads();

    const int ty = tid >> 4, tx = tid & 15;
    float acc[4][8];
    #pragma unroll
    for (int i = 0; i < 4; ++i)
        #pragma unroll
        for (int j = 0; j < 8; ++j) acc[i][j] = 0.f;

    #pragma unroll 2
    for (int d = 0; d < DIM; ++d) {
        const float* wrow = Wt + d * DIM + tx * 8;
        float4 w0 = *(const float4*)wrow;
        float4 w1 = *(const float4*)(wrow + 4);
        float hv[4];
        #pragma unroll
        for (int i = 0; i < 4; ++i) hv[i] = hs[ty * 4 + i][d];
        #pragma unroll
        for (int i = 0; i < 4; ++i) {
            acc[i][0] = fmaf(hv[i], w0.x, acc[i][0]);
            acc[i][1] = fmaf(hv[i], w0.y, acc[i][1]);
            acc[i][2] = fmaf(hv[i], w0.z, acc[i][2]);
            acc[i][3] = fmaf(hv[i], w0.w, acc[i][3]);
            acc[i][4] = fmaf(hv[i], w1.x, acc[i][4]);
            acc[i][5] = fmaf(hv[i], w1.y, acc[i][5]);
            acc[i][6] = fmaf(hv[i], w1.z, acc[i][6]);
            acc[i][7] = fmaf(hv[i], w1.w, acc[i][7]);
        }
    }
    #pragma unroll
    for (int i = 0; i < 4; ++i) {
        float* orow = outp + (size_t)(n0 + ty * 4 + i) * DIM + tx * 8;
        *(float4*)orow       = make_float4(acc[i][0], acc[i][1], acc[i][2], acc[i][3]);
        *(float4*)(orow + 4) = make_float4(acc[i][4], acc[i][5], acc[i][6], acc[i][7]);
    }
}

// Per-relation node transform (score phase): tf[n] = src[n] @ W (block-diag heads)
__global__ __launch_bounds__(256) void trans_kernel(
    const float* __restrict__ src,
    const float* __restrict__ W,
    float* __restrict__ tf)
{
    __shared__ float hs[64][140];
    __shared__ float Ws[4124];
    const int tid = threadIdx.x;
    const int n0 = blockIdx.x * 64;

    const float4* hsrc = (const float4*)(src + (size_t)n0 * DIM);
    #pragma unroll
    for (int i = 0; i < 8; ++i) {
        int f = tid + i * 256;
        int c4 = f & 31;
        int pc4 = c4 + (c4 >> 3);
        *(float4*)&hs[f >> 5][pc4 * 4] = hsrc[f];
    }
    #pragma unroll
    for (int i = 0; i < 16; ++i) {
        int g = tid + i * 256;
        Ws[(g >> 10) * 1028 + (g & 1023)] = W[g];
    }
    __syncthreads();

    const int ty = tid >> 4, tx = tid & 15;
    const int hh = tx >> 2, j8 = (tx & 3) * 8;
    const float* wsb = &Ws[hh * 1028 + j8];
    float acc[4][8];
    #pragma unroll
    for (int i = 0; i < 4; ++i)
        #pragma unroll
        for (int j = 0; j < 8; ++j) acc[i][j] = 0.f;

    #pragma unroll 4
    for (int kk = 0; kk < 32; ++kk) {
        float4 w0 = *(const float4*)(wsb + kk * 32);
        float4 w1 = *(const float4*)(wsb + kk * 32 + 4);
        float hv[4];
        #pragma unroll
        for (int i = 0; i < 4; ++i) hv[i] = hs[ty * 4 + i][hh * 36 + kk];
        #pragma unroll
        for (int i = 0; i < 4; ++i) {
            acc[i][0] = fmaf(hv[i], w0.x, acc[i][0]);
            acc[i][1] = fmaf(hv[i], w0.y, acc[i][1]);
            acc[i][2] = fmaf(hv[i], w0.z, acc[i][2]);
            acc[i][3] = fmaf(hv[i], w0.w, acc[i][3]);
            acc[i][4] = fmaf(hv[i], w1.x, acc[i][4]);
            acc[i][5] = fmaf(hv[i], w1.y, acc[i][5]);
            acc[i][6] = fmaf(hv[i], w1.z, acc[i][6]);
            acc[i][7] = fmaf(hv[i], w1.w, acc[i][7]);
        }
    }
    #pragma unroll
    for (int i = 0; i < 4; ++i) {
        float* orow = tf + (size_t)(n0 + ty * 4 + i) * DIM + hh * 32 + j8;
        *(float4*)orow       = make_float4(acc[i][0], acc[i][1], acc[i][2], acc[i][3]);
        *(float4*)(orow + 4) = make_float4(acc[i][4], acc[i][5], acc[i][6], acc[i][7]);
    }
}

// All-relations v transform: vhat[r][n] = vf[n] @ Wmsg[r]  (h tile loaded once)
__global__ __launch_bounds__(256) void vhat_all(
    const float* __restrict__ vf,
    const float* __restrict__ Wmsg,     // [8][4][32][32]
    float* __restrict__ vhat)           // [8][N][128]
{
    __shared__ float hs[64][140];
    __shared__ float Ws[4124];
    const int tid = threadIdx.x;
    const int n0 = blockIdx.x * 64;

    const float4* hsrc = (const float4*)(vf + (size_t)n0 * DIM);
    #pragma unroll
    for (int i = 0; i < 8; ++i) {
        int f = tid + i * 256;
        int c4 = f & 31;
        int pc4 = c4 + (c4 >> 3);
        *(float4*)&hs[f >> 5][pc4 * 4] = hsrc[f];
    }

    const int ty = tid >> 4, tx = tid & 15;
    const int hh = tx >> 2, j8 = (tx & 3) * 8;

    for (int r = 0; r < N_RELS; ++r) {
        __syncthreads();   // protect Ws from previous iteration's readers
        #pragma unroll
        for (int i = 0; i < 16; ++i) {
            int g = tid + i * 256;
            Ws[(g >> 10) * 1028 + (g & 1023)] = Wmsg[(size_t)r * 4096 + g];
        }
        __syncthreads();

        const float* wsb = &Ws[hh * 1028 + j8];
        float acc[4][8];
        #pragma unroll
        for (int i = 0; i < 4; ++i)
            #pragma unroll
            for (int j = 0; j < 8; ++j) acc[i][j] = 0.f;

        #pragma unroll 4
        for (int kk = 0; kk < 32; ++kk) {
            float4 w0 = *(const float4*)(wsb + kk * 32);
            float4 w1 = *(const float4*)(wsb + kk * 32 + 4);
            float hv[4];
            #pragma unroll
            for (int i = 0; i < 4; ++i) hv[i] = hs[ty * 4 + i][hh * 36 + kk];
            #pragma unroll
            for (int i = 0; i < 4; ++i) {
                acc[i][0] = fmaf(hv[i], w0.x, acc[i][0]);
                acc[i][1] = fmaf(hv[i], w0.y, acc[i][1]);
                acc[i][2] = fmaf(hv[i], w0.z, acc[i][2]);
                acc[i][3] = fmaf(hv[i], w0.w, acc[i][3]);
                acc[i][4] = fmaf(hv[i], w1.x, acc[i][4]);
                acc[i][5] = fmaf(hv[i], w1.y, acc[i][5]);
                acc[i][6] = fmaf(hv[i], w1.z, acc[i][6]);
                acc[i][7] = fmaf(hv[i], w1.w, acc[i][7]);
            }
        }
        float* obase = vhat + (size_t)r * N_NODES * DIM;
        #pragma unroll
        for (int i = 0; i < 4; ++i) {
            float* orow = obase + (size_t)(n0 + ty * 4 + i) * DIM + hh * 32 + j8;
            *(float4*)orow       = make_float4(acc[i][0], acc[i][1], acc[i][2], acc[i][3]);
            *(float4*)(orow + 4) = make_float4(acc[i][4], acc[i][5], acc[i][6], acc[i][7]);
        }
    }
}

// ---------------- edge scoring ----------------

__global__ __launch_bounds__(256) void score_light(
    const float* __restrict__ tf, const float* __restrict__ kf,
    const float* __restrict__ pri,
    const int* __restrict__ row_idx, const int* __restrict__ col_idx,
    float* __restrict__ evals, float* __restrict__ denom,
    int e0, int r)
{
    const int tid = threadIdx.x;
    const int lane = tid & 31;
    const int hh = lane >> 3;
    const int eslot = tid >> 5;
    const float prih = pri[r * N_HEADS + hh] * INV_SQRT_DK;
    int e = e0 + blockIdx.x * 32 + eslot;
    #pragma unroll
    for (int it = 0; it < 4; ++it, e += 8) {
        const int src = row_idx[e];
        const int dst = col_idx[e];
        float4 a = *(const float4*)(tf + (size_t)dst * DIM + lane * 4);
        float4 b = *(const float4*)(kf + (size_t)src * DIM + lane * 4);
        float p = a.x * b.x + a.y * b.y + a.z * b.z + a.w * b.w;
        p += __shfl_xor(p, 1);
        p += __shfl_xor(p, 2);
        p += __shfl_xor(p, 4);
        if ((lane & 7) == 0) {
            float ev = expf(p * prih);
            evals[(size_t)e * N_HEADS + hh] = ev;
            atomicAdd(denom + (size_t)dst * N_HEADS + hh, ev);
        }
    }
}

// ---------------- CSR build ----------------

__global__ __launch_bounds__(256) void hist_kernel(
    const int* __restrict__ col, int* __restrict__ cnt)
{
    int e = blockIdx.x * 256 + threadIdx.x;
    atomicAdd(&cnt[col[e]], 1);
}

__global__ __launch_bounds__(256) void scan1_kernel(
    const int* __restrict__ cnt, int* __restrict__ off, int* __restrict__ bsum)
{
    __shared__ int s[256];
    int g = blockIdx.x * 256 + threadIdx.x;
    int v = cnt[g];
    s[threadIdx.x] = v;
    __syncthreads();
    #pragma unroll
    for (int d = 1; d < 256; d <<= 1) {
        int t = (threadIdx.x >= d) ? s[threadIdx.x - d] : 0;
        __syncthreads();
        s[threadIdx.x] += t;
        __syncthreads();
    }
    off[g] = s[threadIdx.x] - v;
    if (threadIdx.x == 255) bsum[blockIdx.x] = s[255];
}

__global__ __launch_bounds__(256) void scan2_kernel(int* __restrict__ bsum, int nb)
{
    __shared__ int s[256];
    int v = (threadIdx.x < nb) ? bsum[threadIdx.x] : 0;
    s[threadIdx.x] = v;
    __syncthreads();
    #pragma unroll
    for (int d = 1; d < 256; d <<= 1) {
        int t = (threadIdx.x >= d) ? s[threadIdx.x - d] : 0;
        __syncthreads();
        s[threadIdx.x] += t;
        __syncthreads();
    }
    if (threadIdx.x < nb) bsum[threadIdx.x] = s[threadIdx.x] - v;
}

__global__ __launch_bounds__(256) void scan3_kernel(
    int* __restrict__ off, const int* __restrict__ bsum, int* __restrict__ cursor)
{
    int g = blockIdx.x * 256 + threadIdx.x;
    int o = off[g] + bsum[blockIdx.x];
    off[g] = o;
    cursor[g] = o;
}

__global__ __launch_bounds__(256) void scatter_kernel(
    const int* __restrict__ col, int* __restrict__ cursor, int* __restrict__ elist)
{
    int e = blockIdx.x * 256 + threadIdx.x;
    int pos = atomicAdd(&cursor[col[e]], 1);
    elist[pos] = e;
}

// ---------------- pull aggregation (no fp atomics) ----------------

__global__ __launch_bounds__(256) void agg_pull(
    const float* __restrict__ vhat,     // [8][N][128]
    const int* __restrict__ row_idx,
    const int* __restrict__ off,        // [N]
    const int* __restrict__ cnt,        // [N]
    const int* __restrict__ elist,      // [E]
    const float* __restrict__ evals,    // [E][4]
    const float* __restrict__ denom,    // [N][4]
    float* __restrict__ agg)            // [N][128]
{
    const int tid = threadIdx.x;
    const int n = blockIdx.x * 2 + (tid >> 7);
    const int d = tid & 127;
    const int hh = d >> 5;
    const int beg = off[n];
    const int num = cnt[n];
    const float rden = 1.f / (denom[(size_t)n * 4 + hh] + 1e-16f);
    float acc = 0.f;
    int i = 0;
    for (; i + 2 <= num; i += 2) {
        const int e0 = elist[beg + i];
        const int e1 = elist[beg + i + 1];
        const unsigned r0 = (unsigned)e0 / EDGES_PER_REL;
        const unsigned r1 = (unsigned)e1 / EDGES_PER_REL;
        const int s0 = row_idx[e0];
        const int s1 = row_idx[e1];
        const float a0 = evals[(size_t)e0 * 4 + hh] * rden;
        const float a1 = evals[(size_t)e1 * 4 + hh] * rden;
        const float v0 = vhat[(((size_t)r0 * N_NODES + s0) << 7) + d];
        const float v1 = vhat[(((size_t)r1 * N_NODES + s1) << 7) + d];
        acc = fmaf(a0, v0, acc);
        acc = fmaf(a1, v1, acc);
    }
    if (i < num) {
        const int e0 = elist[beg + i];
        const unsigned r0 = (unsigned)e0 / EDGES_PER_REL;
        const int s0 = row_idx[e0];
        const float a0 = evals[(size_t)e0 * 4 + hh] * rden;
        acc = fmaf(a0, vhat[(((size_t)r0 * N_NODES + s0) << 7) + d], acc);
    }
    agg[((size_t)n << 7) + d] = acc;
}

// ---------------- fallback push aggregation (R2 path) ----------------

__global__ __launch_bounds__(256) void msg_light(
    const float* __restrict__ tf,
    const int* __restrict__ row_idx, const int* __restrict__ col_idx,
    const float* __restrict__ evals, const float* __restrict__ denom,
    float* __restrict__ agg, int e0)
{
    const int tid = threadIdx.x;
    const int lane = tid & 31;
    const int hh = lane >> 3;
    const int eslot = tid >> 5;
    int e = e0 + blockIdx.x * 32 + eslot;
    #pragma unroll
    for (int it = 0; it < 4; ++it, e += 8) {
        const int src = row_idx[e];
        const int dst = col_idx[e];
        float4 v4 = *(const float4*)(tf + (size_t)src * DIM + lane * 4);
        float alpha = evals[(size_t)e * N_HEADS + hh]
                    / (denom[(size_t)dst * N_HEADS + hh] + 1e-16f);
        float* ap = agg + (size_t)dst * DIM + lane * 4;
        atomicAdd(ap + 0, alpha * v4.x);
        atomicAdd(ap + 1, alpha * v4.y);
        atomicAdd(ap + 2, alpha * v4.z);
        atomicAdd(ap + 3, alpha * v4.w);
    }
}

// ---------------- output projection ----------------

__global__ __launch_bounds__(256) void out_kernel(
    const float* __restrict__ agg,
    const float* __restrict__ A,
    const float* __restrict__ skip,
    float* __restrict__ outp)
{
    __shared__ float hs[64][132];
    const int tid = threadIdx.x;
    const int n0 = blockIdx.x * 64;
    const int t = n0 / NODES_PER_TYPE;
    const float* Wt = A + (size_t)t * DIM * DIM;
    const float sg = 1.f / (1.f + expf(-skip[t]));

    const float4* hsrc = (const float4*)(agg + (size_t)n0 * DIM);
    #pragma unroll
    for (int i = 0; i < 8; ++i) {
        int f = tid + i * 256;
        *(float4*)&hs[f >> 5][(f & 31) * 4] = hsrc[f];
    }
    __syncthreads();

    const int ty = tid >> 4, tx = tid & 15;
    float acc[4][8];
    #pragma unroll
    for (int i = 0; i < 4; ++i)
        #pragma unroll
        for (int j = 0; j < 8; ++j) acc[i][j] = 0.f;

    #pragma unroll 2
    for (int d = 0; d < DIM; ++d) {
        const float* wrow = Wt + d * DIM + tx * 8;
        float4 w0 = *(const float4*)wrow;
        float4 w1 = *(const float4*)(wrow + 4);
        float hv[4];
        #pragma unroll
        for (int i = 0; i < 4; ++i) hv[i] = hs[ty * 4 + i][d];
        #pragma unroll
        for (int i = 0; i < 4; ++i) {
            acc[i][0] = fmaf(hv[i], w0.x, acc[i][0]);
            acc[i][1] = fmaf(hv[i], w0.y, acc[i][1]);
            acc[i][2] = fmaf(hv[i], w0.z, acc[i][2]);
            acc[i][3] = fmaf(hv[i], w0.w, acc[i][3]);
            acc[i][4] = fmaf(hv[i], w1.x, acc[i][4]);
            acc[i][5] = fmaf(hv[i], w1.y, acc[i][5]);
            acc[i][6] = fmaf(hv[i], w1.z, acc[i][6]);
            acc[i][7] = fmaf(hv[i], w1.w, acc[i][7]);
        }
    }
    #pragma unroll
    for (int i = 0; i < 4; ++i) {
        float* orow = outp + (size_t)(n0 + ty * 4 + i) * DIM + tx * 8;
        *(float4*)orow       = make_float4(sg*acc[i][0], sg*acc[i][1], sg*acc[i][2], sg*acc[i][3]);
        *(float4*)(orow + 4) = make_float4(sg*acc[i][4], sg*acc[i][5], sg*acc[i][6], sg*acc[i][7]);
    }
}

extern "C" void kernel_launch(void* const* d_in, const int* in_sizes, int n_in,
                              void* d_out, int out_size, void* d_ws, size_t ws_size,
                              hipStream_t stream) {
    (void)in_sizes; (void)n_in; (void)out_size;
    const float* h    = (const float*)d_in[0];
    const float* Wk   = (const float*)d_in[1];
    const float* Wq   = (const float*)d_in[2];
    const float* Wv   = (const float*)d_in[3];
    const float* Wa   = (const float*)d_in[4];
    const float* Watt = (const float*)d_in[5];
    const float* Wmsg = (const float*)d_in[6];
    const float* pri  = (const float*)d_in[7];
    const float* skip = (const float*)d_in[8];
    const int* row_idx = (const int*)d_in[9];
    const int* col_idx = (const int*)d_in[10];

    float* out = (float*)d_out;
    float* ws  = (float*)d_ws;

    const size_t NF = (size_t)N_NODES * DIM;                // 6.5536M floats
    const size_t REL_W = (size_t)N_HEADS * D_K * D_K;       // 4096

    // evals (E*4) + denom (N*4) staged in d_out (overwritten by out_kernel)
    float* evals = out;
    float* denom = out + (size_t)N_EDGES * N_HEADS;

    const size_t full_need = 13 * NF * 4 + ((size_t)3 * N_NODES + N_EDGES) * 4;

    if (ws_size >= full_need) {
        // -------- full path: CSR + pull aggregation --------
        float* kf   = ws;
        float* qf   = ws + NF;
        float* vf   = ws + 2 * NF;
        float* tf   = ws + 3 * NF;
        float* vhat = ws + 4 * NF;          // [8][N][128]
        float* agg  = ws + 12 * NF;
        int*  ibase = (int*)(ws + 13 * NF);
        int* cnt    = ibase;
        int* off    = ibase + N_NODES;
        int* cursor = ibase + 2 * N_NODES;
        int* elist  = ibase + 3 * N_NODES;

        // zero denom + cnt
        zero_kernel<<<(N_NODES * N_HEADS / 4 + 255) / 256, 256, 0, stream>>>(denom, N_NODES * N_HEADS / 4);
        zero_kernel<<<(N_NODES / 4 + 255) / 256, 256, 0, stream>>>((float*)cnt, N_NODES / 4);
        // projections
        proj_kernel<<<dim3(N_NODES / 64, 3), 256, 0, stream>>>(h, Wk, Wq, Wv, kf, qf, vf);
        // CSR build (overlaps nothing; independent of projections)
        hist_kernel<<<N_EDGES / 256, 256, 0, stream>>>(col_idx, cnt);
        scan1_kernel<<<N_NODES / 256, 256, 0, stream>>>(cnt, off, cursor /*tmp bsum*/);
        scan2_kernel<<<1, 256, 0, stream>>>(cursor, N_NODES / 256);
        scan3_kernel<<<N_NODES / 256, 256, 0, stream>>>(off, cursor, cursor);
        // note: scan3 rewrites cursor[g] = final offset (bsum consumed per-block first)
        scatter_kernel<<<N_EDGES / 256, 256, 0, stream>>>(col_idx, cursor, elist);
        // score phase (per relation)
        for (int r = 0; r < N_RELS; ++r) {
            trans_kernel<<<N_NODES / 64, 256, 0, stream>>>(qf, Watt + r * REL_W, tf);
            score_light<<<EDGES_PER_REL / 32, 256, 0, stream>>>(
                tf, kf, pri, row_idx, col_idx, evals, denom, r * EDGES_PER_REL, r);
        }
        // all-relation v transform + pull aggregation
        vhat_all<<<N_NODES / 64, 256, 0, stream>>>(vf, Wmsg, vhat);
        agg_pull<<<N_NODES / 2, 256, 0, stream>>>(
            vhat, row_idx, off, cnt, elist, evals, denom, agg);
        out_kernel<<<N_NODES / 64, 256, 0, stream>>>(agg, Wa, skip, out);
    } else {
        // -------- fallback: R2 atomic push path --------
        float* kf = ws;
        float* qf = ws + NF;
        float* vf = ws + 2 * NF;
        float* tf = ws + 3 * NF;
        float* agg = qf;

        zero_kernel<<<(N_NODES * N_HEADS / 4 + 255) / 256, 256, 0, stream>>>(denom, N_NODES * N_HEADS / 4);
        proj_kernel<<<dim3(N_NODES / 64, 3), 256, 0, stream>>>(h, Wk, Wq, Wv, kf, qf, vf);
        for (int r = 0; r < N_RELS; ++r) {
            trans_kernel<<<N_NODES / 64, 256, 0, stream>>>(qf, Watt + r * REL_W, tf);
            score_light<<<EDGES_PER_REL / 32, 256, 0, stream>>>(
                tf, kf, pri, row_idx, col_idx, evals, denom, r * EDGES_PER_REL, r);
        }
        zero_kernel<<<(N_NODES * DIM / 4 + 255) / 256, 256, 0, stream>>>(agg, N_NODES * DIM / 4);
        for (int r = 0; r < N_RELS; ++r) {
            trans_kernel<<<N_NODES / 64, 256, 0, stream>>>(vf, Wmsg + r * REL_W, tf);
            msg_light<<<EDGES_PER_REL / 32, 256, 0, stream>>>(
                tf, row_idx, col_idx, evals, denom, agg, r * EDGES_PER_REL);
        }
        out_kernel<<<N_NODES / 64, 256, 0, stream>>>(agg, Wa, skip, out);
    }
}

// Round 4
// 876.282 us; speedup vs baseline: 1.8320x; 1.8265x over previous
//
#include <hip/hip_runtime.h>
#include <math.h>

#define N_NODES 51200
#define N_EDGES 640000
#define N_TYPES 4
#define N_RELS  8
#define N_HEADS 4
#define D_K     32
#define DIM     128
#define NODES_PER_TYPE (N_NODES / N_TYPES)   // 12800
#define EDGES_PER_REL  (N_EDGES / N_RELS)    // 80000
#define INV_SQRT_DK 0.17677669529663687f

__global__ __launch_bounds__(256) void zero_kernel(float* __restrict__ p, int n4) {
    int i = blockIdx.x * blockDim.x + threadIdx.x;
    if (i < n4) ((float4*)p)[i] = make_float4(0.f, 0.f, 0.f, 0.f);
}

// ---------------- dense projections ----------------

__global__ __launch_bounds__(256) void proj_kernel(
    const float* __restrict__ h,
    const float* __restrict__ Wk,
    const float* __restrict__ Wq,
    const float* __restrict__ Wv,
    float* __restrict__ kf, float* __restrict__ qf, float* __restrict__ vf)
{
    __shared__ float hs[64][132];
    const int tid = threadIdx.x;
    const int which = blockIdx.y;
    const float* W = (which == 0) ? Wk : (which == 1) ? Wq : Wv;
    float* outp    = (which == 0) ? kf : (which == 1) ? qf : vf;
    const int n0 = blockIdx.x * 64;
    const int t = n0 / NODES_PER_TYPE;
    const float* Wt = W + (size_t)t * DIM * DIM;

    const float4* hsrc = (const float4*)(h + (size_t)n0 * DIM);
    #pragma unroll
    for (int i = 0; i < 8; ++i) {
        int f = tid + i * 256;
        *(float4*)&hs[f >> 5][(f & 31) * 4] = hsrc[f];
    }
    __syncthreads();

    const int ty = tid >> 4, tx = tid & 15;
    float acc[4][8];
    #pragma unroll
    for (int i = 0; i < 4; ++i)
        #pragma unroll
        for (int j = 0; j < 8; ++j) acc[i][j] = 0.f;

    #pragma unroll 2
    for (int d = 0; d < DIM; ++d) {
        const float* wrow = Wt + d * DIM + tx * 8;
        float4 w0 = *(const float4*)wrow;
        float4 w1 = *(const float4*)(wrow + 4);
        float hv[4];
        #pragma unroll
        for (int i = 0; i < 4; ++i) hv[i] = hs[ty * 4 + i][d];
        #pragma unroll
        for (int i = 0; i < 4; ++i) {
            acc[i][0] = fmaf(hv[i], w0.x, acc[i][0]);
            acc[i][1] = fmaf(hv[i], w0.y, acc[i][1]);
            acc[i][2] = fmaf(hv[i], w0.z, acc[i][2]);
            acc[i][3] = fmaf(hv[i], w0.w, acc[i][3]);
            acc[i][4] = fmaf(hv[i], w1.x, acc[i][4]);
            acc[i][5] = fmaf(hv[i], w1.y, acc[i][5]);
            acc[i][6] = fmaf(hv[i], w1.z, acc[i][6]);
            acc[i][7] = fmaf(hv[i], w1.w, acc[i][7]);
        }
    }
    #pragma unroll
    for (int i = 0; i < 4; ++i) {
        float* orow = outp + (size_t)(n0 + ty * 4 + i) * DIM + tx * 8;
        *(float4*)orow       = make_float4(acc[i][0], acc[i][1], acc[i][2], acc[i][3]);
        *(float4*)(orow + 4) = make_float4(acc[i][4], acc[i][5], acc[i][6], acc[i][7]);
    }
}

// Per-relation per-head transform: tf[n][h*32+j] = sum_k src[n][h*32+k] * W[h][k][j]
__global__ __launch_bounds__(256) void trans_kernel(
    const float* __restrict__ src,
    const float* __restrict__ W,
    float* __restrict__ tf)
{
    __shared__ float hs[64][140];
    __shared__ float Ws[4124];
    const int tid = threadIdx.x;
    const int n0 = blockIdx.x * 64;

    const float4* hsrc = (const float4*)(src + (size_t)n0 * DIM);
    #pragma unroll
    for (int i = 0; i < 8; ++i) {
        int f = tid + i * 256;
        int c4 = f & 31;
        int pc4 = c4 + (c4 >> 3);
        *(float4*)&hs[f >> 5][pc4 * 4] = hsrc[f];
    }
    #pragma unroll
    for (int i = 0; i < 16; ++i) {
        int g = tid + i * 256;
        Ws[(g >> 10) * 1028 + (g & 1023)] = W[g];
    }
    __syncthreads();

    const int ty = tid >> 4, tx = tid & 15;
    const int hh = tx >> 2, j8 = (tx & 3) * 8;
    const float* wsb = &Ws[hh * 1028 + j8];
    float acc[4][8];
    #pragma unroll
    for (int i = 0; i < 4; ++i)
        #pragma unroll
        for (int j = 0; j < 8; ++j) acc[i][j] = 0.f;

    #pragma unroll 4
    for (int kk = 0; kk < 32; ++kk) {
        float4 w0 = *(const float4*)(wsb + kk * 32);
        float4 w1 = *(const float4*)(wsb + kk * 32 + 4);
        float hv[4];
        #pragma unroll
        for (int i = 0; i < 4; ++i) hv[i] = hs[ty * 4 + i][hh * 36 + kk];
        #pragma unroll
        for (int i = 0; i < 4; ++i) {
            acc[i][0] = fmaf(hv[i], w0.x, acc[i][0]);
            acc[i][1] = fmaf(hv[i], w0.y, acc[i][1]);
            acc[i][2] = fmaf(hv[i], w0.z, acc[i][2]);
            acc[i][3] = fmaf(hv[i], w0.w, acc[i][3]);
            acc[i][4] = fmaf(hv[i], w1.x, acc[i][4]);
            acc[i][5] = fmaf(hv[i], w1.y, acc[i][5]);
            acc[i][6] = fmaf(hv[i], w1.z, acc[i][6]);
            acc[i][7] = fmaf(hv[i], w1.w, acc[i][7]);
        }
    }
    #pragma unroll
    for (int i = 0; i < 4; ++i) {
        float* orow = tf + (size_t)(n0 + ty * 4 + i) * DIM + hh * 32 + j8;
        *(float4*)orow       = make_float4(acc[i][0], acc[i][1], acc[i][2], acc[i][3]);
        *(float4*)(orow + 4) = make_float4(acc[i][4], acc[i][5], acc[i][6], acc[i][7]);
    }
}

// ---------------- edge scoring (no atomics) ----------------

__global__ __launch_bounds__(256) void score_light(
    const float* __restrict__ tf, const float* __restrict__ kf,
    const float* __restrict__ pri,
    const int* __restrict__ row_idx, const int* __restrict__ col_idx,
    float* __restrict__ evals,
    int e0, int r)
{
    const int tid = threadIdx.x;
    const int lane = tid & 31;
    const int hh = lane >> 3;
    const int eslot = tid >> 5;
    const float prih = pri[r * N_HEADS + hh] * INV_SQRT_DK;
    int e = e0 + blockIdx.x * 32 + eslot;
    #pragma unroll
    for (int it = 0; it < 4; ++it, e += 8) {
        const int src = row_idx[e];
        const int dst = col_idx[e];
        float4 a = *(const float4*)(tf + (size_t)dst * DIM + lane * 4);
        float4 b = *(const float4*)(kf + (size_t)src * DIM + lane * 4);
        float p = a.x * b.x + a.y * b.y + a.z * b.z + a.w * b.w;
        p += __shfl_xor(p, 1);
        p += __shfl_xor(p, 2);
        p += __shfl_xor(p, 4);
        if ((lane & 7) == 0)
            evals[(size_t)e * N_HEADS + hh] = expf(p * prih);
    }
}

// ---------------- CSR build: buckets keyed by (rel, dst) ----------------

__global__ __launch_bounds__(256) void hist_kernel(
    const int* __restrict__ col, int* __restrict__ cnt)
{
    int e = blockIdx.x * 256 + threadIdx.x;
    int r = (unsigned)e / EDGES_PER_REL;
    atomicAdd(&cnt[r * N_NODES + col[e]], 1);
}

__global__ __launch_bounds__(256) void scan1_kernel(
    const int* __restrict__ cnt, int* __restrict__ off, int* __restrict__ bsum)
{
    __shared__ int s[256];
    int g = blockIdx.x * 256 + threadIdx.x;
    int v = cnt[g];
    s[threadIdx.x] = v;
    __syncthreads();
    #pragma unroll
    for (int d = 1; d < 256; d <<= 1) {
        int t = (threadIdx.x >= d) ? s[threadIdx.x - d] : 0;
        __syncthreads();
        s[threadIdx.x] += t;
        __syncthreads();
    }
    off[g] = s[threadIdx.x] - v;
    if (threadIdx.x == 255) bsum[blockIdx.x] = s[255];
}

// single-block sequential-chunk scan of nb block sums (nb can exceed 256)
__global__ __launch_bounds__(256) void scan2_kernel(int* __restrict__ bsum, int nb)
{
    __shared__ int s[256];
    __shared__ int carry;
    const int tid = threadIdx.x;
    if (tid == 0) carry = 0;
    __syncthreads();
    for (int base = 0; base < nb; base += 256) {
        int i = base + tid;
        int v = (i < nb) ? bsum[i] : 0;
        s[tid] = v;
        __syncthreads();
        #pragma unroll
        for (int d = 1; d < 256; d <<= 1) {
            int t = (tid >= d) ? s[tid - d] : 0;
            __syncthreads();
            s[tid] += t;
            __syncthreads();
        }
        int incl = s[tid];
        if (i < nb) bsum[i] = carry + incl - v;   // exclusive
        __syncthreads();
        if (tid == 255) carry += incl;
        __syncthreads();
    }
}

__global__ __launch_bounds__(256) void scan3_kernel(
    int* __restrict__ off, const int* __restrict__ bsum, int* __restrict__ cursor)
{
    int g = blockIdx.x * 256 + threadIdx.x;
    int o = off[g] + bsum[blockIdx.x];
    off[g] = o;
    cursor[g] = o;
}

__global__ __launch_bounds__(256) void scatter_kernel(
    const int* __restrict__ col, int* __restrict__ cursor, int* __restrict__ elist)
{
    int e = blockIdx.x * 256 + threadIdx.x;
    int r = (unsigned)e / EDGES_PER_REL;
    int pos = atomicAdd(&cursor[r * N_NODES + col[e]], 1);
    elist[pos] = e;
}

// den[n][h] = sum over all in-edges of exp-scores
__global__ __launch_bounds__(256) void denom_pull(
    const int* __restrict__ off, const int* __restrict__ cnt,
    const int* __restrict__ elist, const float* __restrict__ evals,
    float* __restrict__ den)
{
    int g = blockIdx.x * 256 + threadIdx.x;       // g in [0, N*4)
    int n = g >> 2, hh = g & 3;
    float s = 0.f;
    #pragma unroll
    for (int r = 0; r < N_RELS; ++r) {
        int b = off[r * N_NODES + n];
        int m = cnt[r * N_NODES + n];
        for (int i = 0; i < m; ++i) {
            int e = elist[b + i];
            s += evals[(size_t)e * 4 + hh];
        }
    }
    den[g] = s;
}

// ---------------- pull aggregation, one relation per pass ----------------

template<bool FIRST>
__global__ __launch_bounds__(256) void agg_rel(
    const float* __restrict__ tf,       // vhat for this relation
    const int* __restrict__ row_idx,
    const int* __restrict__ off,        // + r*N
    const int* __restrict__ cnt,        // + r*N
    const int* __restrict__ elist,
    const float* __restrict__ evals,
    float* __restrict__ U)
{
    const int tid = threadIdx.x;
    const int n = blockIdx.x * 2 + (tid >> 7);
    const int d = tid & 127;
    const int hh = d >> 5;
    const int num = cnt[n];
    float acc;
    if (FIRST) {
        acc = 0.f;
    } else {
        if (num == 0) return;                 // wave-uniform early out
        acc = U[((size_t)n << 7) + d];
    }
    const int beg = off[n];
    for (int i = 0; i < num; ++i) {
        const int e = elist[beg + i];
        const float ev = evals[(size_t)e * 4 + hh];
        const int s = row_idx[e];
        acc = fmaf(ev, tf[((size_t)s << 7) + d], acc);
    }
    U[((size_t)n << 7) + d] = acc;
}

// U[n][d] /= (den[n][h]+eps)
__global__ __launch_bounds__(256) void norm_kernel(
    float* __restrict__ U, const float* __restrict__ den)
{
    int i = blockIdx.x * 256 + threadIdx.x;   // float4 index
    float4 u = ((float4*)U)[i];
    int fidx = i << 2;
    int n = fidx >> 7, hh = (fidx >> 5) & 3;
    float r = 1.f / (den[n * 4 + hh] + 1e-16f);
    u.x *= r; u.y *= r; u.z *= r; u.w *= r;
    ((float4*)U)[i] = u;
}

// ---------------- output projection ----------------

__global__ __launch_bounds__(256) void out_kernel(
    const float* __restrict__ agg,
    const float* __restrict__ A,
    const float* __restrict__ skip,
    float* __restrict__ outp)
{
    __shared__ float hs[64][132];
    const int tid = threadIdx.x;
    const int n0 = blockIdx.x * 64;
    const int t = n0 / NODES_PER_TYPE;
    const float* Wt = A + (size_t)t * DIM * DIM;
    const float sg = 1.f / (1.f + expf(-skip[t]));

    const float4* hsrc = (const float4*)(agg + (size_t)n0 * DIM);
    #pragma unroll
    for (int i = 0; i < 8; ++i) {
        int f = tid + i * 256;
        *(float4*)&hs[f >> 5][(f & 31) * 4] = hsrc[f];
    }
    __syncthreads();

    const int ty = tid >> 4, tx = tid & 15;
    float acc[4][8];
    #pragma unroll
    for (int i = 0; i < 4; ++i)
        #pragma unroll
        for (int j = 0; j < 8; ++j) acc[i][j] = 0.f;

    #pragma unroll 2
    for (int d = 0; d < DIM; ++d) {
        const float* wrow = Wt + d * DIM + tx * 8;
        float4 w0 = *(const float4*)wrow;
        float4 w1 = *(const float4*)(wrow + 4);
        float hv[4];
        #pragma unroll
        for (int i = 0; i < 4; ++i) hv[i] = hs[ty * 4 + i][d];
        #pragma unroll
        for (int i = 0; i < 4; ++i) {
            acc[i][0] = fmaf(hv[i], w0.x, acc[i][0]);
            acc[i][1] = fmaf(hv[i], w0.y, acc[i][1]);
            acc[i][2] = fmaf(hv[i], w0.z, acc[i][2]);
            acc[i][3] = fmaf(hv[i], w0.w, acc[i][3]);
            acc[i][4] = fmaf(hv[i], w1.x, acc[i][4]);
            acc[i][5] = fmaf(hv[i], w1.y, acc[i][5]);
            acc[i][6] = fmaf(hv[i], w1.z, acc[i][6]);
            acc[i][7] = fmaf(hv[i], w1.w, acc[i][7]);
        }
    }
    #pragma unroll
    for (int i = 0; i < 4; ++i) {
        float* orow = outp + (size_t)(n0 + ty * 4 + i) * DIM + tx * 8;
        *(float4*)orow       = make_float4(sg*acc[i][0], sg*acc[i][1], sg*acc[i][2], sg*acc[i][3]);
        *(float4*)(orow + 4) = make_float4(sg*acc[i][4], sg*acc[i][5], sg*acc[i][6], sg*acc[i][7]);
    }
}

extern "C" void kernel_launch(void* const* d_in, const int* in_sizes, int n_in,
                              void* d_out, int out_size, void* d_ws, size_t ws_size,
                              hipStream_t stream) {
    (void)in_sizes; (void)n_in; (void)out_size; (void)ws_size;
    const float* h    = (const float*)d_in[0];
    const float* Wk   = (const float*)d_in[1];
    const float* Wq   = (const float*)d_in[2];
    const float* Wv   = (const float*)d_in[3];
    const float* Wa   = (const float*)d_in[4];
    const float* Watt = (const float*)d_in[5];
    const float* Wmsg = (const float*)d_in[6];
    const float* pri  = (const float*)d_in[7];
    const float* skip = (const float*)d_in[8];
    const int* row_idx = (const int*)d_in[9];
    const int* col_idx = (const int*)d_in[10];

    float* out = (float*)d_out;
    float* ws  = (float*)d_ws;

    const size_t NF = (size_t)N_NODES * DIM;            // 6.5536M floats
    const size_t REL_W = (size_t)N_HEADS * D_K * D_K;   // 4096

    // ws (proven budget 4*NF = 104.9 MB): kf | qf | vf | tf ; U overlays qf
    float* kf = ws;
    float* qf = ws + NF;
    float* vf = ws + 2 * NF;
    float* tf = ws + 3 * NF;
    float* U  = qf;

    // d_out staging (consumed before out_kernel overwrites):
    //   evals[E*4] | den[N*4] | cnt[8N] | off[8N] | bsum[1600] | cursor[8N] | elist[E]
    float* evals = out;                                     // 2,560,000 floats
    float* den   = out + (size_t)N_EDGES * N_HEADS;         // +204,800
    int*   cnt    = (int*)(den + (size_t)N_NODES * N_HEADS);
    int*   off    = cnt + (size_t)N_RELS * N_NODES;
    int*   bsum   = off + (size_t)N_RELS * N_NODES;
    int*   cursor = bsum + 1600;
    int*   elist  = cursor + (size_t)N_RELS * N_NODES;
    const int NBUCK = N_RELS * N_NODES;                     // 409600

    // 1. zero bucket counts
    zero_kernel<<<NBUCK / 4 / 256, 256, 0, stream>>>((float*)cnt, NBUCK / 4);
    // 2. K/Q/V projections
    proj_kernel<<<dim3(N_NODES / 64, 3), 256, 0, stream>>>(h, Wk, Wq, Wv, kf, qf, vf);
    // 3. CSR build over (rel, dst) buckets
    hist_kernel<<<N_EDGES / 256, 256, 0, stream>>>(col_idx, cnt);
    scan1_kernel<<<NBUCK / 256, 256, 0, stream>>>(cnt, off, bsum);
    scan2_kernel<<<1, 256, 0, stream>>>(bsum, NBUCK / 256);
    scan3_kernel<<<NBUCK / 256, 256, 0, stream>>>(off, bsum, cursor);
    scatter_kernel<<<N_EDGES / 256, 256, 0, stream>>>(col_idx, cursor, elist);
    // 4. score phase: per relation, dense q-transform + gather-dot (no atomics)
    for (int r = 0; r < N_RELS; ++r) {
        trans_kernel<<<N_NODES / 64, 256, 0, stream>>>(qf, Watt + r * REL_W, tf);
        score_light<<<EDGES_PER_REL / 32, 256, 0, stream>>>(
            tf, kf, pri, row_idx, col_idx, evals, r * EDGES_PER_REL, r);
    }
    // 5. softmax denominators via CSR pull
    denom_pull<<<N_NODES * N_HEADS / 256, 256, 0, stream>>>(off, cnt, elist, evals, den);
    // 6. aggregation: per relation, dense v-transform + pull accumulate (U = qf overlay)
    for (int r = 0; r < N_RELS; ++r) {
        trans_kernel<<<N_NODES / 64, 256, 0, stream>>>(vf, Wmsg + r * REL_W, tf);
        if (r == 0)
            agg_rel<true><<<N_NODES / 2, 256, 0, stream>>>(
                tf, row_idx, off, cnt, elist, evals, U);
        else
            agg_rel<false><<<N_NODES / 2, 256, 0, stream>>>(
                tf, row_idx, off + r * N_NODES, cnt + r * N_NODES, elist, evals, U);
    }
    // 7. normalize U by denominators
    norm_kernel<<<NF / 4 / 256, 256, 0, stream>>>(U, den);
    // 8. output projection
    out_kernel<<<N_NODES / 64, 256, 0, stream>>>(U, Wa, skip, out);
}

// Round 5
// 775.068 us; speedup vs baseline: 2.0712x; 1.1306x over previous
//
#include <hip/hip_runtime.h>
#include <math.h>

#define N_NODES 51200
#define N_EDGES 640000
#define N_TYPES 4
#define N_RELS  8
#define N_HEADS 4
#define D_K     32
#define DIM     128
#define NODES_PER_TYPE (N_NODES / N_TYPES)   // 12800
#define EDGES_PER_REL  (N_EDGES / N_RELS)    // 80000
#define INV_SQRT_DK 0.17677669529663687f

typedef __attribute__((ext_vector_type(8))) short bf16x8;
typedef __attribute__((ext_vector_type(4))) float f32x4;

__device__ inline float bf2f(ushort u) {
    union { unsigned u; float f; } x; x.u = ((unsigned)u) << 16; return x.f;
}
__device__ inline ushort f2bf(float f) {
    union { float f; unsigned u; } x; x.f = f;
    unsigned r = x.u + 0x7FFF + ((x.u >> 16) & 1);
    return (ushort)(r >> 16);
}

// MFMA A/B fragment from bf16 memory: lane's 4 elems at p, next 4 at p+16
// (16x16x32 split-half layout: k = (l>>4)*4+{0..3} and 16+(l>>4)*4+{0..3})
__device__ inline bf16x8 ldfrag(const ushort* p) {
    ushort4 a = *(const ushort4*)p;
    ushort4 b = *(const ushort4*)(p + 16);
    bf16x8 f;
    f[0]=(short)a.x; f[1]=(short)a.y; f[2]=(short)a.z; f[3]=(short)a.w;
    f[4]=(short)b.x; f[5]=(short)b.y; f[6]=(short)b.z; f[7]=(short)b.w;
    return f;
}
__device__ inline bf16x8 ldfrag_f32(const float* p) {
    float4 a = *(const float4*)p;
    float4 b = *(const float4*)(p + 16);
    bf16x8 f;
    f[0]=(short)f2bf(a.x); f[1]=(short)f2bf(a.y); f[2]=(short)f2bf(a.z); f[3]=(short)f2bf(a.w);
    f[4]=(short)f2bf(b.x); f[5]=(short)f2bf(b.y); f[6]=(short)f2bf(b.z); f[7]=(short)f2bf(b.w);
    return f;
}

__global__ __launch_bounds__(256) void zero_kernel(float* __restrict__ p, int n4) {
    int i = blockIdx.x * blockDim.x + threadIdx.x;
    if (i < n4) ((float4*)p)[i] = make_float4(0.f, 0.f, 0.f, 0.f);
}

// h fp32 -> bf16
__global__ __launch_bounds__(256) void cvt_h(const float* __restrict__ h, ushort* __restrict__ hb) {
    int i = blockIdx.x * 256 + threadIdx.x;       // float4 index
    float4 v = ((const float4*)h)[i];
    ushort4 o; o.x=f2bf(v.x); o.y=f2bf(v.y); o.z=f2bf(v.z); o.w=f2bf(v.w);
    ((ushort4*)hb)[i] = o;
}

// Transpose + bf16-convert all weights once.
// WT layout (ushort units): WkT 0 | WqT 65536 | WvT 131072 | WaT 196608 |
//                           WattT 262144 | WmsgT 294912   (totals 327680)
__global__ __launch_bounds__(256) void prep_weights(
    const float* __restrict__ Wk, const float* __restrict__ Wq,
    const float* __restrict__ Wv, const float* __restrict__ Wa,
    const float* __restrict__ Watt, const float* __restrict__ Wmsg,
    ushort* __restrict__ WT)
{
    int g = blockIdx.x * 256 + threadIdx.x;
    if (g < 262144) {
        int which = g >> 16;
        int rem = g & 65535;
        int t = rem >> 14, idx = rem & 16383;
        int d = idx >> 7, o = idx & 127;
        const float* src = (which==0)?Wk:(which==1)?Wq:(which==2)?Wv:Wa;
        WT[(size_t)which*65536 + t*16384 + o*128 + d] = f2bf(src[t*16384 + d*128 + o]);
    } else {
        int g2 = g - 262144;
        int which = g2 >> 15;
        int rem = g2 & 32767;
        int rh = rem >> 10, idx = rem & 1023;
        int k = idx >> 5, j = idx & 31;
        const float* src = which ? Wmsg : Watt;
        WT[262144 + which*32768 + rh*1024 + j*32 + k] = f2bf(src[rh*1024 + k*32 + j]);
    }
}

// K/Q/V projection, MFMA: out[64xN tile][128] = hb @ W[type]; K=128
__global__ __launch_bounds__(256) void proj_mfma(
    const ushort* __restrict__ hb, const ushort* __restrict__ WT,
    ushort* __restrict__ kb, ushort* __restrict__ qb, ushort* __restrict__ vb)
{
    const int tid = threadIdx.x;
    const int which = blockIdx.y;
    ushort* outp = (which == 0) ? kb : (which == 1) ? qb : vb;
    const int n0 = blockIdx.x * 64;
    const int t = n0 / NODES_PER_TYPE;
    const ushort* Wb = WT + (size_t)which*65536 + t*16384;   // [o][d] bf16

    const int wv = tid >> 6, l = tid & 63;
    const int rc = l & 15, kg = (l >> 4) * 4;
    const ushort* Abase = hb + (size_t)(n0 + wv*16 + rc) * DIM;

    bf16x8 af[4];
    #pragma unroll
    for (int kt = 0; kt < 4; ++kt) af[kt] = ldfrag(Abase + kt*32 + kg);

    #pragma unroll
    for (int ct = 0; ct < 8; ++ct) {
        f32x4 acc = {0.f, 0.f, 0.f, 0.f};
        const ushort* Bcol = Wb + (size_t)(ct*16 + rc) * DIM + kg;
        #pragma unroll
        for (int kt = 0; kt < 4; ++kt)
            acc = __builtin_amdgcn_mfma_f32_16x16x32_bf16(af[kt], ldfrag(Bcol + kt*32), acc, 0, 0, 0);
        const int col = ct*16 + rc;
        #pragma unroll
        for (int i = 0; i < 4; ++i)
            outp[(size_t)(n0 + wv*16 + (l>>4)*4 + i) * DIM + col] = f2bf(acc[i]);
    }
}

// Per-relation q-transform, block-diag heads: tf = qb @ Watt[r]; K=32 per head
__global__ __launch_bounds__(256) void trans_mfma(
    const ushort* __restrict__ qb, const ushort* __restrict__ WattS,  // + r*4096
    ushort* __restrict__ tfb)
{
    const int tid = threadIdx.x;
    const int n0 = blockIdx.x * 64;
    const int wv = tid >> 6, l = tid & 63;
    const int rc = l & 15, kg = (l >> 4) * 4;
    const ushort* Abase = qb + (size_t)(n0 + wv*16 + rc) * DIM;

    bf16x8 af[4];
    #pragma unroll
    for (int hh = 0; hh < 4; ++hh) af[hh] = ldfrag(Abase + hh*32 + kg);

    #pragma unroll
    for (int ct = 0; ct < 8; ++ct) {
        const int hh = ct >> 1, jb = (ct & 1) * 16;
        f32x4 acc = {0.f, 0.f, 0.f, 0.f};
        const ushort* Bcol = WattS + hh*1024 + (size_t)(jb + rc) * 32 + kg;
        acc = __builtin_amdgcn_mfma_f32_16x16x32_bf16(af[hh], ldfrag(Bcol), acc, 0, 0, 0);
        const int col = hh*32 + jb + rc;
        #pragma unroll
        for (int i = 0; i < 4; ++i)
            tfb[(size_t)(n0 + wv*16 + (l>>4)*4 + i) * DIM + col] = f2bf(acc[i]);
    }
}

// Edge score: dot32 per head of tf[dst], kb[src] (bf16 gathers), exp, store
__global__ __launch_bounds__(256) void score_light(
    const ushort* __restrict__ tfb, const ushort* __restrict__ kb,
    const float* __restrict__ pri,
    const int* __restrict__ row_idx, const int* __restrict__ col_idx,
    float* __restrict__ evals, int e0, int r)
{
    const int tid = threadIdx.x;
    const int lane = tid & 31;
    const int hh = lane >> 3;
    const int eslot = tid >> 5;
    const float prih = pri[r * N_HEADS + hh] * INV_SQRT_DK;
    int e = e0 + blockIdx.x * 32 + eslot;
    #pragma unroll
    for (int it = 0; it < 4; ++it, e += 8) {
        const int src = row_idx[e];
        const int dst = col_idx[e];
        ushort4 ua = *(const ushort4*)(tfb + (size_t)dst * DIM + lane * 4);
        ushort4 ub = *(const ushort4*)(kb  + (size_t)src * DIM + lane * 4);
        float p = bf2f(ua.x)*bf2f(ub.x) + bf2f(ua.y)*bf2f(ub.y)
                + bf2f(ua.z)*bf2f(ub.z) + bf2f(ua.w)*bf2f(ub.w);
        p += __shfl_xor(p, 1);
        p += __shfl_xor(p, 2);
        p += __shfl_xor(p, 4);
        if ((lane & 7) == 0)
            evals[(size_t)e * N_HEADS + hh] = expf(p * prih);
    }
}

// ---------------- CSR build over (rel, dst) buckets ----------------

__global__ __launch_bounds__(256) void hist_kernel(
    const int* __restrict__ col, int* __restrict__ cnt)
{
    int e = blockIdx.x * 256 + threadIdx.x;
    int r = (unsigned)e / EDGES_PER_REL;
    atomicAdd(&cnt[r * N_NODES + col[e]], 1);
}

__global__ __launch_bounds__(256) void scan1_kernel(
    const int* __restrict__ cnt, int* __restrict__ off, int* __restrict__ bsum)
{
    __shared__ int s[256];
    int g = blockIdx.x * 256 + threadIdx.x;
    int v = cnt[g];
    s[threadIdx.x] = v;
    __syncthreads();
    #pragma unroll
    for (int d = 1; d < 256; d <<= 1) {
        int t = (threadIdx.x >= d) ? s[threadIdx.x - d] : 0;
        __syncthreads();
        s[threadIdx.x] += t;
        __syncthreads();
    }
    off[g] = s[threadIdx.x] - v;
    if (threadIdx.x == 255) bsum[blockIdx.x] = s[255];
}

__global__ __launch_bounds__(256) void scan2_kernel(int* __restrict__ bsum, int nb)
{
    __shared__ int s[256];
    __shared__ int carry;
    const int tid = threadIdx.x;
    if (tid == 0) carry = 0;
    __syncthreads();
    for (int base = 0; base < nb; base += 256) {
        int i = base + tid;
        int v = (i < nb) ? bsum[i] : 0;
        s[tid] = v;
        __syncthreads();
        #pragma unroll
        for (int d = 1; d < 256; d <<= 1) {
            int t = (tid >= d) ? s[tid - d] : 0;
            __syncthreads();
            s[tid] += t;
            __syncthreads();
        }
        int incl = s[tid];
        if (i < nb) bsum[i] = carry + incl - v;
        __syncthreads();
        if (tid == 255) carry += incl;
        __syncthreads();
    }
}

__global__ __launch_bounds__(256) void scan3_kernel(
    int* __restrict__ off, const int* __restrict__ bsum, int* __restrict__ cursor)
{
    int g = blockIdx.x * 256 + threadIdx.x;
    int o = off[g] + bsum[blockIdx.x];
    off[g] = o;
    cursor[g] = o;
}

__global__ __launch_bounds__(256) void scatter_kernel(
    const int* __restrict__ col, int* __restrict__ cursor, int* __restrict__ elist)
{
    int e = blockIdx.x * 256 + threadIdx.x;
    int r = (unsigned)e / EDGES_PER_REL;
    int pos = atomicAdd(&cursor[r * N_NODES + col[e]], 1);
    elist[pos] = e;
}

__global__ __launch_bounds__(256) void denom_pull(
    const int* __restrict__ off, const int* __restrict__ cnt,
    const int* __restrict__ elist, const float* __restrict__ evals,
    float* __restrict__ den)
{
    int g = blockIdx.x * 256 + threadIdx.x;
    int n = g >> 2, hh = g & 3;
    float s = 0.f;
    #pragma unroll
    for (int r = 0; r < N_RELS; ++r) {
        int b = off[r * N_NODES + n];
        int m = cnt[r * N_NODES + n];
        for (int i = 0; i < m; ++i) {
            int e = elist[b + i];
            s += evals[(size_t)e * 4 + hh];
        }
    }
    den[g] = s;
}

// Y_r[n][d] = (1/den) * sum_{e in (r,n)} ev_e * v[src_e][d], 4 relations per pass
__global__ __launch_bounds__(256) void ypull(
    const ushort* __restrict__ vb,
    const int* __restrict__ row_idx,
    const int* __restrict__ off, const int* __restrict__ cnt,
    const int* __restrict__ elist, const float* __restrict__ evals,
    const float* __restrict__ den,
    ushort* __restrict__ Y0, ushort* __restrict__ Y1,
    ushort* __restrict__ Y2, ushort* __restrict__ Y3, int r0)
{
    const int tid = threadIdx.x;
    const int n = blockIdx.x * 2 + (tid >> 7);
    const int d = tid & 127;
    const int hh = d >> 5;
    const float rden = 1.f / (den[(size_t)n * 4 + hh] + 1e-16f);
    ushort* Ys[4] = {Y0, Y1, Y2, Y3};
    #pragma unroll 4
    for (int rr = 0; rr < 4; ++rr) {
        const int b = off[(r0 + rr) * N_NODES + n];
        const int m = cnt[(r0 + rr) * N_NODES + n];
        float acc = 0.f;
        for (int i = 0; i < m; ++i) {
            const int e = elist[b + i];
            acc = fmaf(evals[(size_t)e * 4 + hh], bf2f(vb[(size_t)row_idx[e] * DIM + d]), acc);
        }
        Ys[rr][(size_t)n * DIM + d] = f2bf(acc * rden);
    }
}

// U += sum_{rr} Y_rr @ Wmsg[r0+rr] (block-diag heads), MFMA
template<bool FIRST>
__global__ __launch_bounds__(256) void agg_gemm(
    const ushort* __restrict__ Y0, const ushort* __restrict__ Y1,
    const ushort* __restrict__ Y2, const ushort* __restrict__ Y3,
    const ushort* __restrict__ WmsgT, int r0, float* __restrict__ U)
{
    const int tid = threadIdx.x;
    const int n0 = blockIdx.x * 64;
    const int wv = tid >> 6, l = tid & 63;
    const int rc = l & 15, kg = (l >> 4) * 4;
    const ushort* Ys[4] = {Y0, Y1, Y2, Y3};
    const size_t arow = (size_t)(n0 + wv*16 + rc) * DIM;

    #pragma unroll
    for (int ct = 0; ct < 8; ++ct) {
        const int hh = ct >> 1, jb = (ct & 1) * 16;
        const int col = hh*32 + jb + rc;
        f32x4 acc;
        if (FIRST) {
            acc[0]=0.f; acc[1]=0.f; acc[2]=0.f; acc[3]=0.f;
        } else {
            #pragma unroll
            for (int i = 0; i < 4; ++i)
                acc[i] = U[(size_t)(n0 + wv*16 + (l>>4)*4 + i) * DIM + col];
        }
        #pragma unroll
        for (int rr = 0; rr < 4; ++rr) {
            bf16x8 a = ldfrag(Ys[rr] + arow + hh*32 + kg);
            const ushort* Bcol = WmsgT + (size_t)(r0+rr)*4096 + hh*1024 + (size_t)(jb + rc) * 32 + kg;
            acc = __builtin_amdgcn_mfma_f32_16x16x32_bf16(a, ldfrag(Bcol), acc, 0, 0, 0);
        }
        #pragma unroll
        for (int i = 0; i < 4; ++i)
            U[(size_t)(n0 + wv*16 + (l>>4)*4 + i) * DIM + col] = acc[i];
    }
}

// out = sigmoid(skip[t]) * (U @ Wa[t]), MFMA, fp32 out
__global__ __launch_bounds__(256) void out_mfma(
    const float* __restrict__ U, const ushort* __restrict__ WT,
    const float* __restrict__ skip, float* __restrict__ outp)
{
    const int tid = threadIdx.x;
    const int n0 = blockIdx.x * 64;
    const int t = n0 / NODES_PER_TYPE;
    const ushort* Wb = WT + 196608 + (size_t)t*16384;
    const float sg = 1.f / (1.f + expf(-skip[t]));

    const int wv = tid >> 6, l = tid & 63;
    const int rc = l & 15, kg = (l >> 4) * 4;
    const float* Abase = U + (size_t)(n0 + wv*16 + rc) * DIM;

    bf16x8 af[4];
    #pragma unroll
    for (int kt = 0; kt < 4; ++kt) af[kt] = ldfrag_f32(Abase + kt*32 + kg);

    #pragma unroll
    for (int ct = 0; ct < 8; ++ct) {
        f32x4 acc = {0.f, 0.f, 0.f, 0.f};
        const ushort* Bcol = Wb + (size_t)(ct*16 + rc) * DIM + kg;
        #pragma unroll
        for (int kt = 0; kt < 4; ++kt)
            acc = __builtin_amdgcn_mfma_f32_16x16x32_bf16(af[kt], ldfrag(Bcol + kt*32), acc, 0, 0, 0);
        const int col = ct*16 + rc;
        #pragma unroll
        for (int i = 0; i < 4; ++i)
            outp[(size_t)(n0 + wv*16 + (l>>4)*4 + i) * DIM + col] = sg * acc[i];
    }
}

extern "C" void kernel_launch(void* const* d_in, const int* in_sizes, int n_in,
                              void* d_out, int out_size, void* d_ws, size_t ws_size,
                              hipStream_t stream) {
    (void)in_sizes; (void)n_in; (void)out_size; (void)ws_size;
    const float* h    = (const float*)d_in[0];
    const float* Wk   = (const float*)d_in[1];
    const float* Wq   = (const float*)d_in[2];
    const float* Wv   = (const float*)d_in[3];
    const float* Wa   = (const float*)d_in[4];
    const float* Watt = (const float*)d_in[5];
    const float* Wmsg = (const float*)d_in[6];
    const float* pri  = (const float*)d_in[7];
    const float* skip = (const float*)d_in[8];
    const int* row_idx = (const int*)d_in[9];
    const int* col_idx = (const int*)d_in[10];

    float* out = (float*)d_out;
    char*  wsb = (char*)d_ws;

    const size_t BF = (size_t)N_NODES * DIM * 2;   // bytes per bf16 node array (13.1 MB)
    // ws map (proven budget 8*BF = 104.86 MB):
    //  0:hb | BF:kb | 2BF:vb | 3BF:qb | 4BF:tfb | 5BF..7BF:U(fp32) | 7BF:WT(640KB)
    //  Y pass chunks overlay dead arrays: Y0=hb, Y1=kb, Y2=qb, Y3=tfb (vb stays live)
    ushort* hb  = (ushort*)(wsb);
    ushort* kb  = (ushort*)(wsb + BF);
    ushort* vb  = (ushort*)(wsb + 2*BF);
    ushort* qb  = (ushort*)(wsb + 3*BF);
    ushort* tfb = (ushort*)(wsb + 4*BF);
    float*  U   = (float*) (wsb + 5*BF);
    ushort* WT  = (ushort*)(wsb + 7*BF);
    ushort* WattT = WT + 262144;
    ushort* WmsgT = WT + 294912;

    // d_out staging (consumed before out_mfma overwrites):
    float* evals = out;                                     // E*4
    float* den   = out + (size_t)N_EDGES * N_HEADS;         // N*4
    int*   cnt    = (int*)(den + (size_t)N_NODES * N_HEADS);
    int*   off    = cnt + (size_t)N_RELS * N_NODES;
    int*   bsum   = off + (size_t)N_RELS * N_NODES;
    int*   cursor = bsum + 1600;
    int*   elist  = cursor + (size_t)N_RELS * N_NODES;
    const int NBUCK = N_RELS * N_NODES;

    // 1. weight prep + h conversion + zero counts
    prep_weights<<<1280, 256, 0, stream>>>(Wk, Wq, Wv, Wa, Watt, Wmsg, WT);
    cvt_h<<<(N_NODES * DIM / 4) / 256, 256, 0, stream>>>(h, hb);
    zero_kernel<<<NBUCK / 4 / 256, 256, 0, stream>>>((float*)cnt, NBUCK / 4);
    // 2. K/Q/V projections (MFMA)
    proj_mfma<<<dim3(N_NODES / 64, 3), 256, 0, stream>>>(hb, WT, kb, qb, vb);
    // 3. CSR build
    hist_kernel<<<N_EDGES / 256, 256, 0, stream>>>(col_idx, cnt);
    scan1_kernel<<<NBUCK / 256, 256, 0, stream>>>(cnt, off, bsum);
    scan2_kernel<<<1, 256, 0, stream>>>(bsum, NBUCK / 256);
    scan3_kernel<<<NBUCK / 256, 256, 0, stream>>>(off, bsum, cursor);
    scatter_kernel<<<N_EDGES / 256, 256, 0, stream>>>(col_idx, cursor, elist);
    // 4. score phase: per relation q-transform (MFMA) + gather-dot
    for (int r = 0; r < N_RELS; ++r) {
        trans_mfma<<<N_NODES / 64, 256, 0, stream>>>(qb, WattT + r * 4096, tfb);
        score_light<<<EDGES_PER_REL / 32, 256, 0, stream>>>(
            tfb, kb, pri, row_idx, col_idx, evals, r * EDGES_PER_REL, r);
    }
    // 5. softmax denominators
    denom_pull<<<N_NODES * N_HEADS / 256, 256, 0, stream>>>(off, cnt, elist, evals, den);
    // 6. aggregation: pull normalized v-sums per relation, then dense W_msg GEMM
    //    pass A: rels 0-3 (Y chunks overlay hb,kb,qb,tfb)
    ypull<<<N_NODES / 2, 256, 0, stream>>>(vb, row_idx, off, cnt, elist, evals, den,
                                           hb, kb, qb, tfb, 0);
    agg_gemm<true><<<N_NODES / 64, 256, 0, stream>>>(hb, kb, qb, tfb, WmsgT, 0, U);
    //    pass B: rels 4-7
    ypull<<<N_NODES / 2, 256, 0, stream>>>(vb, row_idx, off, cnt, elist, evals, den,
                                           hb, kb, qb, tfb, 4);
    agg_gemm<false><<<N_NODES / 64, 256, 0, stream>>>(hb, kb, qb, tfb, WmsgT, 4, U);
    // 7. output projection (MFMA) + skip gate
    out_mfma<<<N_NODES / 64, 256, 0, stream>>>(U, WT, skip, out);
}

// Round 6
// 628.648 us; speedup vs baseline: 2.5537x; 1.2329x over previous
//
#include <hip/hip_runtime.h>
#include <math.h>

#define N_NODES 51200
#define N_EDGES 640000
#define N_TYPES 4
#define N_RELS  8
#define N_HEADS 4
#define D_K     32
#define DIM     128
#define NODES_PER_TYPE (N_NODES / N_TYPES)   // 12800
#define EDGES_PER_REL  (N_EDGES / N_RELS)    // 80000
#define INV_SQRT_DK 0.17677669529663687f

typedef __attribute__((ext_vector_type(8))) short bf16x8;
typedef __attribute__((ext_vector_type(4))) float f32x4;

__device__ inline float bf2f(ushort u) {
    union { unsigned u; float f; } x; x.u = ((unsigned)u) << 16; return x.f;
}
__device__ inline ushort f2bf(float f) {
    union { float f; unsigned u; } x; x.f = f;
    unsigned r = x.u + 0x7FFF + ((x.u >> 16) & 1);
    return (ushort)(r >> 16);
}

// MFMA A/B fragment from bf16 memory (16x16x32 split-half k layout)
__device__ inline bf16x8 ldfrag(const ushort* p) {
    ushort4 a = *(const ushort4*)p;
    ushort4 b = *(const ushort4*)(p + 16);
    bf16x8 f;
    f[0]=(short)a.x; f[1]=(short)a.y; f[2]=(short)a.z; f[3]=(short)a.w;
    f[4]=(short)b.x; f[5]=(short)b.y; f[6]=(short)b.z; f[7]=(short)b.w;
    return f;
}
__device__ inline bf16x8 ldfrag_f32(const float* p) {
    float4 a = *(const float4*)p;
    float4 b = *(const float4*)(p + 16);
    bf16x8 f;
    f[0]=(short)f2bf(a.x); f[1]=(short)f2bf(a.y); f[2]=(short)f2bf(a.z); f[3]=(short)f2bf(a.w);
    f[4]=(short)f2bf(b.x); f[5]=(short)f2bf(b.y); f[6]=(short)f2bf(b.z); f[7]=(short)f2bf(b.w);
    return f;
}

__global__ __launch_bounds__(256) void zero_kernel(float* __restrict__ p, int n4) {
    int i = blockIdx.x * blockDim.x + threadIdx.x;
    if (i < n4) ((float4*)p)[i] = make_float4(0.f, 0.f, 0.f, 0.f);
}

__global__ __launch_bounds__(256) void cvt_h(const float* __restrict__ h, ushort* __restrict__ hb) {
    int i = blockIdx.x * 256 + threadIdx.x;
    float4 v = ((const float4*)h)[i];
    ushort4 o; o.x=f2bf(v.x); o.y=f2bf(v.y); o.z=f2bf(v.z); o.w=f2bf(v.w);
    ((ushort4*)hb)[i] = o;
}

// Transpose + bf16-convert all weights once.
// WT layout (ushort): WkT 0 | WqT 65536 | WvT 131072 | WaT 196608 | WattT 262144 | WmsgT 294912
__global__ __launch_bounds__(256) void prep_weights(
    const float* __restrict__ Wk, const float* __restrict__ Wq,
    const float* __restrict__ Wv, const float* __restrict__ Wa,
    const float* __restrict__ Watt, const float* __restrict__ Wmsg,
    ushort* __restrict__ WT)
{
    int g = blockIdx.x * 256 + threadIdx.x;
    if (g < 262144) {
        int which = g >> 16;
        int rem = g & 65535;
        int t = rem >> 14, idx = rem & 16383;
        int d = idx >> 7, o = idx & 127;
        const float* src = (which==0)?Wk:(which==1)?Wq:(which==2)?Wv:Wa;
        WT[(size_t)which*65536 + t*16384 + o*128 + d] = f2bf(src[t*16384 + d*128 + o]);
    } else {
        int g2 = g - 262144;
        int which = g2 >> 15;
        int rem = g2 & 32767;
        int rh = rem >> 10, idx = rem & 1023;
        int k = idx >> 5, j = idx & 31;
        const float* src = which ? Wmsg : Watt;
        WT[262144 + which*32768 + rh*1024 + j*32 + k] = f2bf(src[rh*1024 + k*32 + j]);
    }
}

// K/Q/V projection, MFMA
__global__ __launch_bounds__(256) void proj_mfma(
    const ushort* __restrict__ hb, const ushort* __restrict__ WT,
    ushort* __restrict__ kb, ushort* __restrict__ qb, ushort* __restrict__ vb)
{
    const int tid = threadIdx.x;
    const int which = blockIdx.y;
    ushort* outp = (which == 0) ? kb : (which == 1) ? qb : vb;
    const int n0 = blockIdx.x * 64;
    const int t = n0 / NODES_PER_TYPE;
    const ushort* Wb = WT + (size_t)which*65536 + t*16384;

    const int wv = tid >> 6, l = tid & 63;
    const int rc = l & 15, kg = (l >> 4) * 4;
    const ushort* Abase = hb + (size_t)(n0 + wv*16 + rc) * DIM;

    bf16x8 af[4];
    #pragma unroll
    for (int kt = 0; kt < 4; ++kt) af[kt] = ldfrag(Abase + kt*32 + kg);

    #pragma unroll
    for (int ct = 0; ct < 8; ++ct) {
        f32x4 acc = {0.f, 0.f, 0.f, 0.f};
        const ushort* Bcol = Wb + (size_t)(ct*16 + rc) * DIM + kg;
        #pragma unroll
        for (int kt = 0; kt < 4; ++kt)
            acc = __builtin_amdgcn_mfma_f32_16x16x32_bf16(af[kt], ldfrag(Bcol + kt*32), acc, 0, 0, 0);
        const int col = ct*16 + rc;
        #pragma unroll
        for (int i = 0; i < 4; ++i)
            outp[(size_t)(n0 + wv*16 + (l>>4)*4 + i) * DIM + col] = f2bf(acc[i]);
    }
}

// Per-relation q-transform (block-diag heads), MFMA
__global__ __launch_bounds__(256) void trans_mfma(
    const ushort* __restrict__ qb, const ushort* __restrict__ WattS,
    ushort* __restrict__ tfb)
{
    const int tid = threadIdx.x;
    const int n0 = blockIdx.x * 64;
    const int wv = tid >> 6, l = tid & 63;
    const int rc = l & 15, kg = (l >> 4) * 4;
    const ushort* Abase = qb + (size_t)(n0 + wv*16 + rc) * DIM;

    bf16x8 af[4];
    #pragma unroll
    for (int hh = 0; hh < 4; ++hh) af[hh] = ldfrag(Abase + hh*32 + kg);

    #pragma unroll
    for (int ct = 0; ct < 8; ++ct) {
        const int hh = ct >> 1, jb = (ct & 1) * 16;
        f32x4 acc = {0.f, 0.f, 0.f, 0.f};
        const ushort* Bcol = WattS + hh*1024 + (size_t)(jb + rc) * 32 + kg;
        acc = __builtin_amdgcn_mfma_f32_16x16x32_bf16(af[hh], ldfrag(Bcol), acc, 0, 0, 0);
        const int col = hh*32 + jb + rc;
        #pragma unroll
        for (int i = 0; i < 4; ++i)
            tfb[(size_t)(n0 + wv*16 + (l>>4)*4 + i) * DIM + col] = f2bf(acc[i]);
    }
}

// ---------------- CSR build over (rel, dst) buckets ----------------

__global__ __launch_bounds__(256) void hist_kernel(
    const int* __restrict__ col, int* __restrict__ cnt)
{
    int e = blockIdx.x * 256 + threadIdx.x;
    int r = (unsigned)e / EDGES_PER_REL;
    atomicAdd(&cnt[r * N_NODES + col[e]], 1);
}

__global__ __launch_bounds__(256) void scan1_kernel(
    const int* __restrict__ cnt, int* __restrict__ off, int* __restrict__ bsum)
{
    __shared__ int s[256];
    int g = blockIdx.x * 256 + threadIdx.x;
    int v = cnt[g];
    s[threadIdx.x] = v;
    __syncthreads();
    #pragma unroll
    for (int d = 1; d < 256; d <<= 1) {
        int t = (threadIdx.x >= d) ? s[threadIdx.x - d] : 0;
        __syncthreads();
        s[threadIdx.x] += t;
        __syncthreads();
    }
    off[g] = s[threadIdx.x] - v;
    if (threadIdx.x == 255) bsum[blockIdx.x] = s[255];
}

__global__ __launch_bounds__(256) void scan2_kernel(int* __restrict__ bsum, int nb)
{
    __shared__ int s[256];
    __shared__ int carry;
    const int tid = threadIdx.x;
    if (tid == 0) carry = 0;
    __syncthreads();
    for (int base = 0; base < nb; base += 256) {
        int i = base + tid;
        int v = (i < nb) ? bsum[i] : 0;
        s[tid] = v;
        __syncthreads();
        #pragma unroll
        for (int d = 1; d < 256; d <<= 1) {
            int t = (tid >= d) ? s[tid - d] : 0;
            __syncthreads();
            s[tid] += t;
            __syncthreads();
        }
        int incl = s[tid];
        if (i < nb) bsum[i] = carry + incl - v;
        __syncthreads();
        if (tid == 255) carry += incl;
        __syncthreads();
    }
}

__global__ __launch_bounds__(256) void scan3_kernel(
    int* __restrict__ off, const int* __restrict__ bsum, int* __restrict__ cursor)
{
    int g = blockIdx.x * 256 + threadIdx.x;
    int o = off[g] + bsum[blockIdx.x];
    off[g] = o;
    cursor[g] = o;
}

__global__ __launch_bounds__(256) void scatter_kernel(
    const int* __restrict__ col, int* __restrict__ cursor, int* __restrict__ elist)
{
    int e = blockIdx.x * 256 + threadIdx.x;
    int r = (unsigned)e / EDGES_PER_REL;
    int pos = atomicAdd(&cursor[r * N_NODES + col[e]], 1);
    elist[pos] = e;
}

// src/dst in elist (CSR) order — removes per-edge indirection downstream
__global__ __launch_bounds__(256) void perm_kernel(
    const int* __restrict__ elist,
    const int* __restrict__ row_idx, const int* __restrict__ col_idx,
    int* __restrict__ srcS, int* __restrict__ dstS)
{
    int p = blockIdx.x * 256 + threadIdx.x;
    int e = elist[p];
    srcS[p] = row_idx[e];
    dstS[p] = col_idx[e];
}

// Edge score in CSR order: contiguous src/dst, near-sequential tf[dst] gathers
__global__ __launch_bounds__(256) void score_sorted(
    const ushort* __restrict__ tfb, const ushort* __restrict__ kb,
    const float* __restrict__ pri,
    const int* __restrict__ srcS, const int* __restrict__ dstS,
    float* __restrict__ evals, int p0, int r)
{
    const int tid = threadIdx.x;
    const int lane = tid & 31;
    const int hh = lane >> 3;
    const int eslot = tid >> 5;
    const float prih = pri[r * N_HEADS + hh] * INV_SQRT_DK;
    int p = p0 + blockIdx.x * 32 + eslot;
    #pragma unroll
    for (int it = 0; it < 4; ++it, p += 8) {
        const int src = srcS[p];
        const int dst = dstS[p];
        ushort4 ua = *(const ushort4*)(tfb + (size_t)dst * DIM + lane * 4);
        ushort4 ub = *(const ushort4*)(kb  + (size_t)src * DIM + lane * 4);
        float s = bf2f(ua.x)*bf2f(ub.x) + bf2f(ua.y)*bf2f(ub.y)
                + bf2f(ua.z)*bf2f(ub.z) + bf2f(ua.w)*bf2f(ub.w);
        s += __shfl_xor(s, 1);
        s += __shfl_xor(s, 2);
        s += __shfl_xor(s, 4);
        if ((lane & 7) == 0)
            evals[(size_t)p * N_HEADS + hh] = expf(s * prih);
    }
}

// den[n][h] = sum of evals over the node's 8 contiguous bucket ranges
__global__ __launch_bounds__(256) void denom_pull(
    const int* __restrict__ off, const int* __restrict__ cnt,
    const float* __restrict__ evals, float* __restrict__ den)
{
    int g = blockIdx.x * 256 + threadIdx.x;
    int n = g >> 2, hh = g & 3;
    float s = 0.f;
    #pragma unroll
    for (int r = 0; r < N_RELS; ++r) {
        int b = off[r * N_NODES + n];
        int m = cnt[r * N_NODES + n];
        for (int i = 0; i < m; ++i)
            s += evals[(size_t)(b + i) * 4 + hh];
    }
    den[g] = s;
}

// Y_r[n][d] = (1/den) * sum_{p in bucket(r,n)} ev_p * v[src_p][d]
// 4 nodes/block, 64 lanes/node, ushort2 per lane. Contiguous ev/src reads.
__global__ __launch_bounds__(256) void ypull(
    const ushort* __restrict__ vb,
    const int* __restrict__ srcS,
    const int* __restrict__ off, const int* __restrict__ cnt,
    const float* __restrict__ evals, const float* __restrict__ den,
    ushort* __restrict__ Y0, ushort* __restrict__ Y1,
    ushort* __restrict__ Y2, ushort* __restrict__ Y3, int r0)
{
    const int tid = threadIdx.x;
    const int n = blockIdx.x * 4 + (tid >> 6);
    const int lane = tid & 63;            // d pair index: d = lane*2
    const int hh = lane >> 4;
    const float rden = 1.f / (den[(size_t)n * 4 + hh] + 1e-16f);
    const uint* vb2 = (const uint*)vb;    // ushort2 as packed uint
    ushort* Ys[4] = {Y0, Y1, Y2, Y3};
    #pragma unroll 4
    for (int rr = 0; rr < 4; ++rr) {
        const int b = off[(r0 + rr) * N_NODES + n];
        const int m = cnt[(r0 + rr) * N_NODES + n];
        float ax = 0.f, ay = 0.f;
        for (int i = 0; i < m; ++i) {
            const int p = b + i;
            const float ev = evals[(size_t)p * 4 + hh];
            const uint v2 = vb2[((size_t)srcS[p] << 6) + lane];
            ax = fmaf(ev, bf2f((ushort)(v2 & 0xffff)), ax);
            ay = fmaf(ev, bf2f((ushort)(v2 >> 16)), ay);
        }
        uint o = (uint)f2bf(ax * rden) | ((uint)f2bf(ay * rden) << 16);
        ((uint*)Ys[rr])[((size_t)n << 6) + lane] = o;
    }
}

// U += sum_{rr} Y_rr @ Wmsg[r0+rr] (block-diag heads), MFMA
template<bool FIRST>
__global__ __launch_bounds__(256) void agg_gemm(
    const ushort* __restrict__ Y0, const ushort* __restrict__ Y1,
    const ushort* __restrict__ Y2, const ushort* __restrict__ Y3,
    const ushort* __restrict__ WmsgT, int r0, float* __restrict__ U)
{
    const int tid = threadIdx.x;
    const int n0 = blockIdx.x * 64;
    const int wv = tid >> 6, l = tid & 63;
    const int rc = l & 15, kg = (l >> 4) * 4;
    const ushort* Ys[4] = {Y0, Y1, Y2, Y3};
    const size_t arow = (size_t)(n0 + wv*16 + rc) * DIM;

    #pragma unroll
    for (int ct = 0; ct < 8; ++ct) {
        const int hh = ct >> 1, jb = (ct & 1) * 16;
        const int col = hh*32 + jb + rc;
        f32x4 acc;
        if (FIRST) {
            acc[0]=0.f; acc[1]=0.f; acc[2]=0.f; acc[3]=0.f;
        } else {
            #pragma unroll
            for (int i = 0; i < 4; ++i)
                acc[i] = U[(size_t)(n0 + wv*16 + (l>>4)*4 + i) * DIM + col];
        }
        #pragma unroll
        for (int rr = 0; rr < 4; ++rr) {
            bf16x8 a = ldfrag(Ys[rr] + arow + hh*32 + kg);
            const ushort* Bcol = WmsgT + (size_t)(r0+rr)*4096 + hh*1024 + (size_t)(jb + rc) * 32 + kg;
            acc = __builtin_amdgcn_mfma_f32_16x16x32_bf16(a, ldfrag(Bcol), acc, 0, 0, 0);
        }
        #pragma unroll
        for (int i = 0; i < 4; ++i)
            U[(size_t)(n0 + wv*16 + (l>>4)*4 + i) * DIM + col] = acc[i];
    }
}

// out = sigmoid(skip[t]) * (U @ Wa[t]), MFMA
__global__ __launch_bounds__(256) void out_mfma(
    const float* __restrict__ U, const ushort* __restrict__ WT,
    const float* __restrict__ skip, float* __restrict__ outp)
{
    const int tid = threadIdx.x;
    const int n0 = blockIdx.x * 64;
    const int t = n0 / NODES_PER_TYPE;
    const ushort* Wb = WT + 196608 + (size_t)t*16384;
    const float sg = 1.f / (1.f + expf(-skip[t]));

    const int wv = tid >> 6, l = tid & 63;
    const int rc = l & 15, kg = (l >> 4) * 4;
    const float* Abase = U + (size_t)(n0 + wv*16 + rc) * DIM;

    bf16x8 af[4];
    #pragma unroll
    for (int kt = 0; kt < 4; ++kt) af[kt] = ldfrag_f32(Abase + kt*32 + kg);

    #pragma unroll
    for (int ct = 0; ct < 8; ++ct) {
        f32x4 acc = {0.f, 0.f, 0.f, 0.f};
        const ushort* Bcol = Wb + (size_t)(ct*16 + rc) * DIM + kg;
        #pragma unroll
        for (int kt = 0; kt < 4; ++kt)
            acc = __builtin_amdgcn_mfma_f32_16x16x32_bf16(af[kt], ldfrag(Bcol + kt*32), acc, 0, 0, 0);
        const int col = ct*16 + rc;
        #pragma unroll
        for (int i = 0; i < 4; ++i)
            outp[(size_t)(n0 + wv*16 + (l>>4)*4 + i) * DIM + col] = sg * acc[i];
    }
}

extern "C" void kernel_launch(void* const* d_in, const int* in_sizes, int n_in,
                              void* d_out, int out_size, void* d_ws, size_t ws_size,
                              hipStream_t stream) {
    (void)in_sizes; (void)n_in; (void)out_size; (void)ws_size;
    const float* h    = (const float*)d_in[0];
    const float* Wk   = (const float*)d_in[1];
    const float* Wq   = (const float*)d_in[2];
    const float* Wv   = (const float*)d_in[3];
    const float* Wa   = (const float*)d_in[4];
    const float* Watt = (const float*)d_in[5];
    const float* Wmsg = (const float*)d_in[6];
    const float* pri  = (const float*)d_in[7];
    const float* skip = (const float*)d_in[8];
    const int* row_idx = (const int*)d_in[9];
    const int* col_idx = (const int*)d_in[10];

    float* out = (float*)d_out;
    char*  wsb = (char*)d_ws;

    const size_t BF = (size_t)N_NODES * DIM * 2;   // bytes per bf16 node array
    // ws map (proven 8*BF = 104.86 MB):
    //  0:hb | BF:kb | 2BF:vb | 3BF:qb | 4BF:tfb | 5BF..7BF:U(fp32) | 7BF:WT
    //  Y chunks overlay dead arrays: Y0=hb, Y1=kb, Y2=qb, Y3=tfb (vb stays live)
    ushort* hb  = (ushort*)(wsb);
    ushort* kb  = (ushort*)(wsb + BF);
    ushort* vb  = (ushort*)(wsb + 2*BF);
    ushort* qb  = (ushort*)(wsb + 3*BF);
    ushort* tfb = (ushort*)(wsb + 4*BF);
    float*  U   = (float*) (wsb + 5*BF);
    ushort* WT  = (ushort*)(wsb + 7*BF);
    ushort* WattT = WT + 262144;
    ushort* WmsgT = WT + 294912;

    // d_out staging (consumed before out_mfma):
    //  evals[E*4] | den[N*4] | cnt[8N] | off[8N] | bsum[1600] | cursor[8N] | elist[E] | srcS[E] | dstS[E]
    float* evals = out;
    float* den   = out + (size_t)N_EDGES * N_HEADS;
    int*   cnt    = (int*)(den + (size_t)N_NODES * N_HEADS);
    int*   off    = cnt + (size_t)N_RELS * N_NODES;
    int*   bsum   = off + (size_t)N_RELS * N_NODES;
    int*   cursor = bsum + 1600;
    int*   elist  = cursor + (size_t)N_RELS * N_NODES;
    int*   srcS   = elist + N_EDGES;
    int*   dstS   = srcS + N_EDGES;
    const int NBUCK = N_RELS * N_NODES;

    // 1. weight prep + h conversion + zero counts
    prep_weights<<<1280, 256, 0, stream>>>(Wk, Wq, Wv, Wa, Watt, Wmsg, WT);
    cvt_h<<<(N_NODES * DIM / 4) / 256, 256, 0, stream>>>(h, hb);
    zero_kernel<<<NBUCK / 4 / 256, 256, 0, stream>>>((float*)cnt, NBUCK / 4);
    // 2. K/Q/V projections (MFMA)
    proj_mfma<<<dim3(N_NODES / 64, 3), 256, 0, stream>>>(hb, WT, kb, qb, vb);
    // 3. CSR build + sorted src/dst
    hist_kernel<<<N_EDGES / 256, 256, 0, stream>>>(col_idx, cnt);
    scan1_kernel<<<NBUCK / 256, 256, 0, stream>>>(cnt, off, bsum);
    scan2_kernel<<<1, 256, 0, stream>>>(bsum, NBUCK / 256);
    scan3_kernel<<<NBUCK / 256, 256, 0, stream>>>(off, bsum, cursor);
    scatter_kernel<<<N_EDGES / 256, 256, 0, stream>>>(col_idx, cursor, elist);
    perm_kernel<<<N_EDGES / 256, 256, 0, stream>>>(elist, row_idx, col_idx, srcS, dstS);
    // 4. score phase: per relation q-transform (MFMA) + sorted gather-dot
    for (int r = 0; r < N_RELS; ++r) {
        trans_mfma<<<N_NODES / 64, 256, 0, stream>>>(qb, WattT + r * 4096, tfb);
        score_sorted<<<EDGES_PER_REL / 32, 256, 0, stream>>>(
            tfb, kb, pri, srcS, dstS, evals, r * EDGES_PER_REL, r);
    }
    // 5. softmax denominators (contiguous evals)
    denom_pull<<<N_NODES * N_HEADS / 256, 256, 0, stream>>>(off, cnt, evals, den);
    // 6. aggregation: pull normalized v-sums (contiguous ev/src), dense W_msg GEMM
    ypull<<<N_NODES / 4, 256, 0, stream>>>(vb, srcS, off, cnt, evals, den,
                                           hb, kb, qb, tfb, 0);
    agg_gemm<true><<<N_NODES / 64, 256, 0, stream>>>(hb, kb, qb, tfb, WmsgT, 0, U);
    ypull<<<N_NODES / 4, 256, 0, stream>>>(vb, srcS, off, cnt, evals, den,
                                           hb, kb, qb, tfb, 4);
    agg_gemm<false><<<N_NODES / 64, 256, 0, stream>>>(hb, kb, qb, tfb, WmsgT, 4, U);
    // 7. output projection (MFMA) + skip gate
    out_mfma<<<N_NODES / 64, 256, 0, stream>>>(U, WT, skip, out);
}

// Round 7
// 512.654 us; speedup vs baseline: 3.1314x; 1.2263x over previous
//
#include <hip/hip_runtime.h>
#include <math.h>

#define N_NODES 51200
#define N_EDGES 640000
#define N_TYPES 4
#define N_RELS  8
#define N_HEADS 4
#define D_K     32
#define DIM     128
#define NODES_PER_TYPE (N_NODES / N_TYPES)   // 12800
#define EDGES_PER_REL  (N_EDGES / N_RELS)    // 80000
#define INV_SQRT_DK 0.17677669529663687f

typedef __attribute__((ext_vector_type(8))) short bf16x8;
typedef __attribute__((ext_vector_type(4))) float f32x4;

__device__ inline float bf2f(ushort u) {
    union { unsigned u; float f; } x; x.u = ((unsigned)u) << 16; return x.f;
}
__device__ inline ushort f2bf(float f) {
    union { float f; unsigned u; } x; x.f = f;
    unsigned r = x.u + 0x7FFF + ((x.u >> 16) & 1);
    return (ushort)(r >> 16);
}
__device__ inline bf16x8 pack8(ushort4 a, ushort4 b) {
    bf16x8 f;
    f[0]=(short)a.x; f[1]=(short)a.y; f[2]=(short)a.z; f[3]=(short)a.w;
    f[4]=(short)b.x; f[5]=(short)b.y; f[6]=(short)b.z; f[7]=(short)b.w;
    return f;
}
// global-memory fragment (split-half k layout), used by agg/out
__device__ inline bf16x8 ldfrag(const ushort* p) {
    return pack8(*(const ushort4*)p, *(const ushort4*)(p + 16));
}
__device__ inline bf16x8 ldfrag_f32(const float* p) {
    float4 a = *(const float4*)p;
    float4 b = *(const float4*)(p + 16);
    bf16x8 f;
    f[0]=(short)f2bf(a.x); f[1]=(short)f2bf(a.y); f[2]=(short)f2bf(a.z); f[3]=(short)f2bf(a.w);
    f[4]=(short)f2bf(b.x); f[5]=(short)f2bf(b.y); f[6]=(short)f2bf(b.z); f[7]=(short)f2bf(b.w);
    return f;
}
// LDS fragment from a [rows][128]-ushort tile, XOR-swizzled (T2): col ^ ((row&7)<<3)
__device__ inline bf16x8 ldsfragA(const ushort* S, int row, int c0) {
    const ushort* p0 = S + row * 128 + ((c0     ) ^ ((row & 7) << 3));
    const ushort* p1 = S + row * 128 + ((c0 + 16) ^ ((row & 7) << 3));
    return pack8(*(const ushort4*)p0, *(const ushort4*)p1);
}

__global__ __launch_bounds__(256) void zero_kernel(float* __restrict__ p, int n4) {
    int i = blockIdx.x * blockDim.x + threadIdx.x;
    if (i < n4) ((float4*)p)[i] = make_float4(0.f, 0.f, 0.f, 0.f);
}

__global__ __launch_bounds__(256) void cvt_h(const float* __restrict__ h, ushort* __restrict__ hb) {
    int i = blockIdx.x * 256 + threadIdx.x;
    float4 v = ((const float4*)h)[i];
    ushort4 o; o.x=f2bf(v.x); o.y=f2bf(v.y); o.z=f2bf(v.z); o.w=f2bf(v.w);
    ((ushort4*)hb)[i] = o;
}

// Transpose + bf16-convert all weights once.
// WT layout (ushort): WkT 0 | WqT 65536 | WvT 131072 | WaT 196608 | WattT 262144 | WmsgT 294912
__global__ __launch_bounds__(256) void prep_weights(
    const float* __restrict__ Wk, const float* __restrict__ Wq,
    const float* __restrict__ Wv, const float* __restrict__ Wa,
    const float* __restrict__ Watt, const float* __restrict__ Wmsg,
    ushort* __restrict__ WT)
{
    int g = blockIdx.x * 256 + threadIdx.x;
    if (g < 262144) {
        int which = g >> 16;
        int rem = g & 65535;
        int t = rem >> 14, idx = rem & 16383;
        int d = idx >> 7, o = idx & 127;
        const float* src = (which==0)?Wk:(which==1)?Wq:(which==2)?Wv:Wa;
        WT[(size_t)which*65536 + t*16384 + o*128 + d] = f2bf(src[t*16384 + d*128 + o]);
    } else {
        int g2 = g - 262144;
        int which = g2 >> 15;
        int rem = g2 & 32767;
        int rh = rem >> 10, idx = rem & 1023;
        int k = idx >> 5, j = idx & 31;
        const float* src = which ? Wmsg : Watt;
        WT[262144 + which*32768 + rh*1024 + j*32 + k] = f2bf(src[rh*1024 + k*32 + j]);
    }
}

// Fused K/Q/V projection: LDS-staged A and W (swizzled), MFMA from LDS,
// C staged through LDS (overlaying W) for coalesced 16-B stores.
__global__ __launch_bounds__(256) void proj_fused(
    const ushort* __restrict__ hb, const ushort* __restrict__ WT,
    ushort* __restrict__ kb, ushort* __restrict__ qb, ushort* __restrict__ vb)
{
    __shared__ ushort As[64 * 128];     // 16 KB
    __shared__ ushort Ws[128 * 128];    // 32 KB; C staging [64][136] overlays after barrier
    const int tid = threadIdx.x;
    const int n0 = blockIdx.x * 64;
    const int t  = n0 / NODES_PER_TYPE;
    const int wv = tid >> 6, l = tid & 63;
    const int rc = l & 15, g = l >> 4, kg = g * 4;
    ushort* Cs = Ws;

    // stage A tile (coalesced 16-B loads -> swizzled LDS)
    #pragma unroll
    for (int rd = 0; rd < 4; ++rd) {
        int f = tid + rd * 256;
        int row = f >> 4, cu = (f & 15) * 8;
        int4 x = *(const int4*)(hb + (size_t)(n0 + row) * DIM + cu);
        *(int4*)(As + row * 128 + (cu ^ ((row & 7) << 3))) = x;
    }
    // stage W for which=0
    {
        const ushort* Wsrc = WT + (size_t)t * 16384;
        #pragma unroll
        for (int rd = 0; rd < 8; ++rd) {
            int f = tid + rd * 256;
            int o = f >> 4, cu = (f & 15) * 8;
            int4 x = *(const int4*)(Wsrc + o * 128 + cu);
            *(int4*)(Ws + o * 128 + (cu ^ ((o & 7) << 3))) = x;
        }
    }
    __syncthreads();

    // A fragments: kept in registers across all 3 projections
    const int arow = wv * 16 + rc;
    bf16x8 af[4];
    #pragma unroll
    for (int kt = 0; kt < 4; ++kt) af[kt] = ldsfragA(As, arow, kt * 32 + kg);

    for (int which = 0; which < 3; ++which) {
        ushort* outp = (which == 0) ? kb : (which == 1) ? qb : vb;

        f32x4 acc[8];
        #pragma unroll
        for (int ct = 0; ct < 8; ++ct) {
            acc[ct][0]=0.f; acc[ct][1]=0.f; acc[ct][2]=0.f; acc[ct][3]=0.f;
            const int orow = ct * 16 + rc;
            #pragma unroll
            for (int kt = 0; kt < 4; ++kt)
                acc[ct] = __builtin_amdgcn_mfma_f32_16x16x32_bf16(
                    af[kt], ldsfragA(Ws, orow, kt * 32 + kg), acc[ct], 0, 0, 0);
        }
        __syncthreads();   // all waves done reading Ws -> reuse as Cs

        #pragma unroll
        for (int ct = 0; ct < 8; ++ct)
            #pragma unroll
            for (int i = 0; i < 4; ++i)
                Cs[(wv * 16 + g * 4 + i) * 136 + ct * 16 + rc] = f2bf(acc[ct][i]);
        __syncthreads();

        // coalesced readout + store
        #pragma unroll
        for (int rd = 0; rd < 4; ++rd) {
            int f = tid + rd * 256;
            int row = f >> 4, cu = (f & 15) * 8;
            int4 x = *(const int4*)(Cs + row * 136 + cu);
            *(int4*)(outp + (size_t)(n0 + row) * DIM + cu) = x;
        }

        if (which < 2) {
            __syncthreads();   // readout done before restaging Ws
            const ushort* Wsrc = WT + (size_t)(which + 1) * 65536 + t * 16384;
            #pragma unroll
            for (int rd = 0; rd < 8; ++rd) {
                int f = tid + rd * 256;
                int o = f >> 4, cu = (f & 15) * 8;
                int4 x = *(const int4*)(Wsrc + o * 128 + cu);
                *(int4*)(Ws + o * 128 + (cu ^ ((o & 7) << 3))) = x;
            }
            __syncthreads();
        }
    }
}

// Per-relation q-transform (block-diag heads): LDS-staged, coalesced stores.
__global__ __launch_bounds__(256) void trans_fused(
    const ushort* __restrict__ qb, const ushort* __restrict__ Wsrc,  // WattT + r*4096
    ushort* __restrict__ tfb)
{
    __shared__ ushort As[64 * 128];   // 16 KB, swizzled
    __shared__ ushort Ws[4096];       // 8 KB, [h][j][k] swizzled at 8-B granularity
    __shared__ ushort Cs[64 * 136];   // 17 KB padded
    const int tid = threadIdx.x;
    const int n0 = blockIdx.x * 64;
    const int wv = tid >> 6, l = tid & 63;
    const int rc = l & 15, g = l >> 4, kg = g * 4;

    #pragma unroll
    for (int rd = 0; rd < 4; ++rd) {
        int f = tid + rd * 256;
        int row = f >> 4, cu = (f & 15) * 8;
        int4 x = *(const int4*)(qb + (size_t)(n0 + row) * DIM + cu);
        *(int4*)(As + row * 128 + (cu ^ ((row & 7) << 3))) = x;
    }
    #pragma unroll
    for (int rd = 0; rd < 4; ++rd) {
        int f = tid + rd * 256;           // 1024 granules of 4 ushorts
        int idx = f * 4;
        ushort4 x = *(const ushort4*)(Wsrc + idx);
        *(ushort4*)(Ws + (idx ^ (((idx >> 5) & 7) << 2))) = x;
    }
    __syncthreads();

    const int arow = wv * 16 + rc;
    bf16x8 af[4];
    #pragma unroll
    for (int hh = 0; hh < 4; ++hh) af[hh] = ldsfragA(As, arow, hh * 32 + kg);

    #pragma unroll
    for (int ct = 0; ct < 8; ++ct) {
        const int hh = ct >> 1, jb = (ct & 1) * 16;
        const int j = jb + rc;
        const int w0 = hh * 1024 + j * 32 + kg;
        bf16x8 bf = pack8(*(const ushort4*)(Ws + ( w0        ^ ((j & 7) << 2))),
                          *(const ushort4*)(Ws + ((w0 + 16)  ^ ((j & 7) << 2))));
        f32x4 acc = {0.f, 0.f, 0.f, 0.f};
        acc = __builtin_amdgcn_mfma_f32_16x16x32_bf16(af[hh], bf, acc, 0, 0, 0);
        const int col = hh * 32 + jb + rc;
        #pragma unroll
        for (int i = 0; i < 4; ++i)
            Cs[(wv * 16 + g * 4 + i) * 136 + col] = f2bf(acc[i]);
    }
    __syncthreads();

    #pragma unroll
    for (int rd = 0; rd < 4; ++rd) {
        int f = tid + rd * 256;
        int row = f >> 4, cu = (f & 15) * 8;
        int4 x = *(const int4*)(Cs + row * 136 + cu);
        *(int4*)(tfb + (size_t)(n0 + row) * DIM + cu) = x;
    }
}

// Edge score in CSR order
__global__ __launch_bounds__(256) void score_sorted(
    const ushort* __restrict__ tfb, const ushort* __restrict__ kb,
    const float* __restrict__ pri,
    const int* __restrict__ srcS, const int* __restrict__ dstS,
    float* __restrict__ evals, int p0, int r)
{
    const int tid = threadIdx.x;
    const int lane = tid & 31;
    const int hh = lane >> 3;
    const int eslot = tid >> 5;
    const float prih = pri[r * N_HEADS + hh] * INV_SQRT_DK;
    int p = p0 + blockIdx.x * 32 + eslot;
    #pragma unroll
    for (int it = 0; it < 4; ++it, p += 8) {
        const int src = srcS[p];
        const int dst = dstS[p];
        ushort4 ua = *(const ushort4*)(tfb + (size_t)dst * DIM + lane * 4);
        ushort4 ub = *(const ushort4*)(kb  + (size_t)src * DIM + lane * 4);
        float s = bf2f(ua.x)*bf2f(ub.x) + bf2f(ua.y)*bf2f(ub.y)
                + bf2f(ua.z)*bf2f(ub.z) + bf2f(ua.w)*bf2f(ub.w);
        s += __shfl_xor(s, 1);
        s += __shfl_xor(s, 2);
        s += __shfl_xor(s, 4);
        if ((lane & 7) == 0)
            evals[(size_t)p * N_HEADS + hh] = expf(s * prih);
    }
}

// ---------------- CSR build over (rel, dst) buckets ----------------

__global__ __launch_bounds__(256) void hist_kernel(
    const int* __restrict__ col, int* __restrict__ cnt)
{
    int e = blockIdx.x * 256 + threadIdx.x;
    int r = (unsigned)e / EDGES_PER_REL;
    atomicAdd(&cnt[r * N_NODES + col[e]], 1);
}

__global__ __launch_bounds__(256) void scan1_kernel(
    const int* __restrict__ cnt, int* __restrict__ off, int* __restrict__ bsum)
{
    __shared__ int s[256];
    int g = blockIdx.x * 256 + threadIdx.x;
    int v = cnt[g];
    s[threadIdx.x] = v;
    __syncthreads();
    #pragma unroll
    for (int d = 1; d < 256; d <<= 1) {
        int t = (threadIdx.x >= d) ? s[threadIdx.x - d] : 0;
        __syncthreads();
        s[threadIdx.x] += t;
        __syncthreads();
    }
    off[g] = s[threadIdx.x] - v;
    if (threadIdx.x == 255) bsum[blockIdx.x] = s[255];
}

__global__ __launch_bounds__(256) void scan2_kernel(int* __restrict__ bsum, int nb)
{
    __shared__ int s[256];
    __shared__ int carry;
    const int tid = threadIdx.x;
    if (tid == 0) carry = 0;
    __syncthreads();
    for (int base = 0; base < nb; base += 256) {
        int i = base + tid;
        int v = (i < nb) ? bsum[i] : 0;
        s[tid] = v;
        __syncthreads();
        #pragma unroll
        for (int d = 1; d < 256; d <<= 1) {
            int t = (tid >= d) ? s[tid - d] : 0;
            __syncthreads();
            s[tid] += t;
            __syncthreads();
        }
        int incl = s[tid];
        if (i < nb) bsum[i] = carry + incl - v;
        __syncthreads();
        if (tid == 255) carry += incl;
        __syncthreads();
    }
}

__global__ __launch_bounds__(256) void scan3_kernel(
    int* __restrict__ off, const int* __restrict__ bsum, int* __restrict__ cursor)
{
    int g = blockIdx.x * 256 + threadIdx.x;
    int o = off[g] + bsum[blockIdx.x];
    off[g] = o;
    cursor[g] = o;
}

// scatter directly materializes sorted src/dst (no elist/perm pass)
__global__ __launch_bounds__(256) void scatter_kernel(
    const int* __restrict__ row, const int* __restrict__ col,
    int* __restrict__ cursor, int* __restrict__ srcS, int* __restrict__ dstS)
{
    int e = blockIdx.x * 256 + threadIdx.x;
    int r = (unsigned)e / EDGES_PER_REL;
    int c = col[e];
    int pos = atomicAdd(&cursor[r * N_NODES + c], 1);
    srcS[pos] = row[e];
    dstS[pos] = c;
}

__global__ __launch_bounds__(256) void denom_pull(
    const int* __restrict__ off, const int* __restrict__ cnt,
    const float* __restrict__ evals, float* __restrict__ den)
{
    int g = blockIdx.x * 256 + threadIdx.x;
    int n = g >> 2, hh = g & 3;
    float s = 0.f;
    #pragma unroll
    for (int r = 0; r < N_RELS; ++r) {
        int b = off[r * N_NODES + n];
        int m = cnt[r * N_NODES + n];
        for (int i = 0; i < m; ++i)
            s += evals[(size_t)(b + i) * 4 + hh];
    }
    den[g] = s;
}

// Y_r[n][d] = (1/den) * sum_{p in bucket(r,n)} ev_p * v[src_p][d]
__global__ __launch_bounds__(256) void ypull(
    const ushort* __restrict__ vb,
    const int* __restrict__ srcS,
    const int* __restrict__ off, const int* __restrict__ cnt,
    const float* __restrict__ evals, const float* __restrict__ den,
    ushort* __restrict__ Y0, ushort* __restrict__ Y1,
    ushort* __restrict__ Y2, ushort* __restrict__ Y3, int r0)
{
    const int tid = threadIdx.x;
    const int n = blockIdx.x * 4 + (tid >> 6);
    const int lane = tid & 63;            // d pair index: d = lane*2
    const int hh = lane >> 4;
    const float rden = 1.f / (den[(size_t)n * 4 + hh] + 1e-16f);
    const uint* vb2 = (const uint*)vb;
    ushort* Ys[4] = {Y0, Y1, Y2, Y3};
    #pragma unroll 4
    for (int rr = 0; rr < 4; ++rr) {
        const int b = off[(r0 + rr) * N_NODES + n];
        const int m = cnt[(r0 + rr) * N_NODES + n];
        float ax = 0.f, ay = 0.f;
        for (int i = 0; i < m; ++i) {
            const int p = b + i;
            const float ev = evals[(size_t)p * 4 + hh];
            const uint v2 = vb2[((size_t)srcS[p] << 6) + lane];
            ax = fmaf(ev, bf2f((ushort)(v2 & 0xffff)), ax);
            ay = fmaf(ev, bf2f((ushort)(v2 >> 16)), ay);
        }
        uint o = (uint)f2bf(ax * rden) | ((uint)f2bf(ay * rden) << 16);
        ((uint*)Ys[rr])[((size_t)n << 6) + lane] = o;
    }
}

// U += sum_{rr} Y_rr @ Wmsg[r0+rr] (block-diag heads), MFMA
template<bool FIRST>
__global__ __launch_bounds__(256) void agg_gemm(
    const ushort* __restrict__ Y0, const ushort* __restrict__ Y1,
    const ushort* __restrict__ Y2, const ushort* __restrict__ Y3,
    const ushort* __restrict__ WmsgT, int r0, float* __restrict__ U)
{
    const int tid = threadIdx.x;
    const int n0 = blockIdx.x * 64;
    const int wv = tid >> 6, l = tid & 63;
    const int rc = l & 15, kg = (l >> 4) * 4;
    const ushort* Ys[4] = {Y0, Y1, Y2, Y3};
    const size_t arow = (size_t)(n0 + wv*16 + rc) * DIM;

    #pragma unroll
    for (int ct = 0; ct < 8; ++ct) {
        const int hh = ct >> 1, jb = (ct & 1) * 16;
        const int col = hh*32 + jb + rc;
        f32x4 acc;
        if (FIRST) {
            acc[0]=0.f; acc[1]=0.f; acc[2]=0.f; acc[3]=0.f;
        } else {
            #pragma unroll
            for (int i = 0; i < 4; ++i)
                acc[i] = U[(size_t)(n0 + wv*16 + (l>>4)*4 + i) * DIM + col];
        }
        #pragma unroll
        for (int rr = 0; rr < 4; ++rr) {
            bf16x8 a = ldfrag(Ys[rr] + arow + hh*32 + kg);
            const ushort* Bcol = WmsgT + (size_t)(r0+rr)*4096 + hh*1024 + (size_t)(jb + rc) * 32 + kg;
            acc = __builtin_amdgcn_mfma_f32_16x16x32_bf16(a, ldfrag(Bcol), acc, 0, 0, 0);
        }
        #pragma unroll
        for (int i = 0; i < 4; ++i)
            U[(size_t)(n0 + wv*16 + (l>>4)*4 + i) * DIM + col] = acc[i];
    }
}

// out = sigmoid(skip[t]) * (U @ Wa[t]), MFMA
__global__ __launch_bounds__(256) void out_mfma(
    const float* __restrict__ U, const ushort* __restrict__ WT,
    const float* __restrict__ skip, float* __restrict__ outp)
{
    const int tid = threadIdx.x;
    const int n0 = blockIdx.x * 64;
    const int t = n0 / NODES_PER_TYPE;
    const ushort* Wb = WT + 196608 + (size_t)t*16384;
    const float sg = 1.f / (1.f + expf(-skip[t]));

    const int wv = tid >> 6, l = tid & 63;
    const int rc = l & 15, kg = (l >> 4) * 4;
    const float* Abase = U + (size_t)(n0 + wv*16 + rc) * DIM;

    bf16x8 af[4];
    #pragma unroll
    for (int kt = 0; kt < 4; ++kt) af[kt] = ldfrag_f32(Abase + kt*32 + kg);

    #pragma unroll
    for (int ct = 0; ct < 8; ++ct) {
        f32x4 acc = {0.f, 0.f, 0.f, 0.f};
        const ushort* Bcol = Wb + (size_t)(ct*16 + rc) * DIM + kg;
        #pragma unroll
        for (int kt = 0; kt < 4; ++kt)
            acc = __builtin_amdgcn_mfma_f32_16x16x32_bf16(af[kt], ldfrag(Bcol + kt*32), acc, 0, 0, 0);
        const int col = ct*16 + rc;
        #pragma unroll
        for (int i = 0; i < 4; ++i)
            outp[(size_t)(n0 + wv*16 + (l>>4)*4 + i) * DIM + col] = sg * acc[i];
    }
}

extern "C" void kernel_launch(void* const* d_in, const int* in_sizes, int n_in,
                              void* d_out, int out_size, void* d_ws, size_t ws_size,
                              hipStream_t stream) {
    (void)in_sizes; (void)n_in; (void)out_size; (void)ws_size;
    const float* h    = (const float*)d_in[0];
    const float* Wk   = (const float*)d_in[1];
    const float* Wq   = (const float*)d_in[2];
    const float* Wv   = (const float*)d_in[3];
    const float* Wa   = (const float*)d_in[4];
    const float* Watt = (const float*)d_in[5];
    const float* Wmsg = (const float*)d_in[6];
    const float* pri  = (const float*)d_in[7];
    const float* skip = (const float*)d_in[8];
    const int* row_idx = (const int*)d_in[9];
    const int* col_idx = (const int*)d_in[10];

    float* out = (float*)d_out;
    char*  wsb = (char*)d_ws;

    const size_t BF = (size_t)N_NODES * DIM * 2;   // bytes per bf16 node array
    // ws map (proven 8*BF = 104.86 MB):
    //  0:hb | BF:kb | 2BF:vb | 3BF:qb | 4BF:tfb | 5BF..7BF:U(fp32) | 7BF:WT
    //  Y chunks overlay dead arrays: Y0=hb, Y1=kb, Y2=qb, Y3=tfb (vb stays live)
    ushort* hb  = (ushort*)(wsb);
    ushort* kb  = (ushort*)(wsb + BF);
    ushort* vb  = (ushort*)(wsb + 2*BF);
    ushort* qb  = (ushort*)(wsb + 3*BF);
    ushort* tfb = (ushort*)(wsb + 4*BF);
    float*  U   = (float*) (wsb + 5*BF);
    ushort* WT  = (ushort*)(wsb + 7*BF);
    ushort* WattT = WT + 262144;
    ushort* WmsgT = WT + 294912;

    // d_out staging (consumed before out_mfma):
    //  evals[E*4] | den[N*4] | cnt[8N] | off[8N] | bsum[1600] | cursor[8N] | srcS[E] | dstS[E]
    float* evals = out;
    float* den   = out + (size_t)N_EDGES * N_HEADS;
    int*   cnt    = (int*)(den + (size_t)N_NODES * N_HEADS);
    int*   off    = cnt + (size_t)N_RELS * N_NODES;
    int*   bsum   = off + (size_t)N_RELS * N_NODES;
    int*   cursor = bsum + 1600;
    int*   srcS   = cursor + (size_t)N_RELS * N_NODES;
    int*   dstS   = srcS + N_EDGES;
    const int NBUCK = N_RELS * N_NODES;

    // 1. weight prep + h conversion + zero counts
    prep_weights<<<1280, 256, 0, stream>>>(Wk, Wq, Wv, Wa, Watt, Wmsg, WT);
    cvt_h<<<(N_NODES * DIM / 4) / 256, 256, 0, stream>>>(h, hb);
    zero_kernel<<<NBUCK / 4 / 256, 256, 0, stream>>>((float*)cnt, NBUCK / 4);
    // 2. fused K/Q/V projection (LDS-staged MFMA)
    proj_fused<<<N_NODES / 64, 256, 0, stream>>>(hb, WT, kb, qb, vb);
    // 3. CSR build + sorted src/dst (scatter writes them directly)
    hist_kernel<<<N_EDGES / 256, 256, 0, stream>>>(col_idx, cnt);
    scan1_kernel<<<NBUCK / 256, 256, 0, stream>>>(cnt, off, bsum);
    scan2_kernel<<<1, 256, 0, stream>>>(bsum, NBUCK / 256);
    scan3_kernel<<<NBUCK / 256, 256, 0, stream>>>(off, bsum, cursor);
    scatter_kernel<<<N_EDGES / 256, 256, 0, stream>>>(row_idx, col_idx, cursor, srcS, dstS);
    // 4. score phase: per relation q-transform (LDS MFMA) + sorted gather-dot
    for (int r = 0; r < N_RELS; ++r) {
        trans_fused<<<N_NODES / 64, 256, 0, stream>>>(qb, WattT + r * 4096, tfb);
        score_sorted<<<EDGES_PER_REL / 32, 256, 0, stream>>>(
            tfb, kb, pri, srcS, dstS, evals, r * EDGES_PER_REL, r);
    }
    // 5. softmax denominators
    denom_pull<<<N_NODES * N_HEADS / 256, 256, 0, stream>>>(off, cnt, evals, den);
    // 6. aggregation: pull normalized v-sums, dense W_msg GEMM
    ypull<<<N_NODES / 4, 256, 0, stream>>>(vb, srcS, off, cnt, evals, den,
                                           hb, kb, qb, tfb, 0);
    agg_gemm<true><<<N_NODES / 64, 256, 0, stream>>>(hb, kb, qb, tfb, WmsgT, 0, U);
    ypull<<<N_NODES / 4, 256, 0, stream>>>(vb, srcS, off, cnt, evals, den,
                                           hb, kb, qb, tfb, 4);
    agg_gemm<false><<<N_NODES / 64, 256, 0, stream>>>(hb, kb, qb, tfb, WmsgT, 4, U);
    // 7. output projection (MFMA) + skip gate
    out_mfma<<<N_NODES / 64, 256, 0, stream>>>(U, WT, skip, out);
}